// Round 8
// baseline (1113.827 us; speedup 1.0000x reference)
//
#include <hip/hip_runtime.h>
#include <math.h>

#define BB 16
#define NN 1024
#define DD 256

typedef unsigned short u16;
typedef unsigned int uint32;
typedef __attribute__((ext_vector_type(8))) short s8v;   // 8 bf16 (4 VGPRs)
typedef __attribute__((ext_vector_type(4))) float f4v;   // 4 fp32 acc

__device__ __forceinline__ u16 f2b(float f) {            // RNE fp32->bf16
  uint32 u = __float_as_uint(f);
  return (u16)((u + 0x7fffu + ((u >> 16) & 1u)) >> 16);
}
__device__ __forceinline__ float b2f(u16 u) {
  return __uint_as_float(((uint32)u) << 16);
}
__device__ __forceinline__ float blo(uint32 w) { return __uint_as_float(w << 16); }
__device__ __forceinline__ float bhi(uint32 w) { return __uint_as_float(w & 0xffff0000u); }

// async global->LDS DMA, 16B per lane; lds base must be wave-uniform (HW scatters +lane*16B)
__device__ __forceinline__ void gld16(u16* lds, const u16* g) {
  __builtin_amdgcn_global_load_lds(
      (const __attribute__((address_space(1))) unsigned int*)g,
      (__attribute__((address_space(3))) unsigned int*)lds, 16, 0, 0);
}

__device__ __forceinline__ float waveRedSum(float v) {
  #pragma unroll
  for (int o = 32; o; o >>= 1) v += __shfl_xor(v, o, 64);
  return v;
}
__device__ __forceinline__ float waveRedMax(float v) {
  #pragma unroll
  for (int o = 32; o; o >>= 1) v = fmaxf(v, __shfl_xor(v, o, 64));
  return v;
}

// ---------------------------------------------------------------- pts [B,N,3]
__global__ void k_pts(const float* __restrict__ x, float* __restrict__ pts) {
  int i = blockIdx.x * 256 + threadIdx.x;
  if (i >= BB * NN) return;
  int b = i >> 10, n = i & 1023;
  const float* xb = x + (size_t)b * 3 * NN;
  pts[i * 3 + 0] = xb[n];
  pts[i * 3 + 1] = xb[NN + n];
  pts[i * 3 + 2] = xb[2 * NN + n];
}

// ---------------------------------------------------------------- eA fp32 [bn][256] float2
__global__ void k_phase(const float* __restrict__ pts, const float* __restrict__ A,
                        float2* __restrict__ eA) {
  int i = blockIdx.x * 256 + threadIdx.x;            // (b*N+n)*256 + d
  int d = i & 255; int bn = i >> 8;
  float p0 = pts[bn * 3], p1 = pts[bn * 3 + 1], p2 = pts[bn * 3 + 2];
  float ta = p0 * A[d] + p1 * A[256 + d] + p2 * A[512 + d];
  float s, c;
  sincosf(ta, &s, &c); eA[i] = make_float2(c, s);
}

// ---------------------------------------------------------------- eA -> eAT bf16 [b][512][1024]
__global__ void k_eat(const float2* __restrict__ eA, u16* __restrict__ eAT) {
  int bid = blockIdx.x;
  int dt = bid & 7, nt = (bid >> 3) & 15, b = bid >> 7;
  int d0 = dt * 32, n0 = nt * 64;
  __shared__ u16 cosT[32][72], sinT[32][72];
  int t = threadIdx.x;
  {
    int n = t >> 2, dg = (t & 3) * 8;
    const float2* p = eA + ((size_t)(b * 1024 + n0 + n)) * 256 + d0 + dg;
    #pragma unroll
    for (int j = 0; j < 8; j++) {
      float2 v = p[j];
      cosT[dg + j][n] = f2b(v.x);
      sinT[dg + j][n] = f2b(v.y);
    }
  }
  __syncthreads();
  {
    int rr = t >> 2, ng = (t & 3) * 16;
    int d = rr >> 1, cmp = rr & 1;
    const u16* src = (cmp ? &sinT[d][ng] : &cosT[d][ng]);
    uint4 v0 = *(const uint4*)src;
    uint4 v1 = *(const uint4*)(src + 8);
    u16* dst = eAT + ((size_t)(b * 512 + 2 * d0 + rr)) * 1024 + n0 + ng;
    *(uint4*)dst = v0;
    *(uint4*)(dst + 8) = v1;
  }
}

// ---------------------------------------------------------------- J bf16 [b][n][1024]
__global__ void k_jbuild(const float* __restrict__ pts, u16* __restrict__ J) {
  int bid = blockIdx.x;                 // b*1024 + n
  int b = bid >> 10, n = bid & 1023;
  int t = threadIdx.x;
  const float* pb = pts + (size_t)b * 3072;
  float pnx = pb[n * 3], pny = pb[n * 3 + 1], pnz = pb[n * 3 + 2];
  int m = t * 4;
  const float* pm = pb + (size_t)m * 3;
  float4 a = *(const float4*)pm;
  float4 bq = *(const float4*)(pm + 4);
  float4 c = *(const float4*)(pm + 8);
  float dx, dy, dz, d2;
  dx = a.x - pnx;  dy = a.y - pny;  dz = a.z - pnz;  d2 = dx*dx + dy*dy + dz*dz;
  float j0 = __expf(-18.0f * d2);
  dx = a.w - pnx;  dy = bq.x - pny; dz = bq.y - pnz; d2 = dx*dx + dy*dy + dz*dz;
  float j1 = __expf(-18.0f * d2);
  dx = bq.z - pnx; dy = bq.w - pny; dz = c.x - pnz;  d2 = dx*dx + dy*dy + dz*dz;
  float j2 = __expf(-18.0f * d2);
  dx = c.y - pnx;  dy = c.z - pny;  dz = c.w - pnz;  d2 = dx*dx + dy*dy + dz*dz;
  float j3 = __expf(-18.0f * d2);
  uint32 lo = (uint32)f2b(j0) | ((uint32)f2b(j1) << 16);
  uint32 hi = (uint32)f2b(j2) | ((uint32)f2b(j3) << 16);
  *(uint2*)(J + (size_t)bid * 1024 + m) = make_uint2(lo, hi);
}

// ------------------------------------------ G = norm(M*conj(eA))*16 + exp(i pts@P) -> interleaved bf16 [bn][512]
__global__ void k_norm(const float2* __restrict__ M, const float2* __restrict__ eA,
                       const float* __restrict__ pts, const float* __restrict__ P,
                       u16* __restrict__ Gb) {
  int bn = blockIdx.x; int c = threadIdx.x;
  size_t idx = (size_t)bn * DD + c;
  float2 m = M[idx], e = eA[idx];
  float gr = m.x * e.x + m.y * e.y;
  float gi = m.y * e.x - m.x * e.y;
  float s = gr * gr + gi * gi;
  s = waveRedSum(s);
  __shared__ float red[4];
  if ((c & 63) == 0) red[c >> 6] = s;
  __syncthreads();
  float tot = red[0] + red[1] + red[2] + red[3];
  float scale = 16.0f / sqrtf(tot);
  float p0 = pts[bn * 3], p1 = pts[bn * 3 + 1], p2 = pts[bn * 3 + 2];
  float tp = p0 * P[c] + p1 * P[256 + c] + p2 * P[512 + c];
  float sp, cp; sincosf(tp, &sp, &cp);
  uint32 pk = (uint32)f2b(gr * scale + cp) | ((uint32)f2b(gi * scale + sp) << 16);
  *(uint32*)(Gb + idx * 2) = pk;
}

// ---------------------------------------------------------------- weight casts / complex-weight prep
__global__ void k_cast(const float* __restrict__ s, u16* __restrict__ d, int n) {
  int i = blockIdx.x * 256 + threadIdx.x;
  if (i < n) d[i] = f2b(s[i]);
}
__global__ void k_wprep(const float* __restrict__ wr, const float* __restrict__ wi,
                        u16* __restrict__ dst) {
  int i = blockIdx.x * 256 + threadIdx.x;   // 512*512
  int op = i >> 9, c2 = i & 511, c = c2 >> 1, pl = c2 & 1;
  float v;
  if (op < 256) v = pl ? -wi[op * 256 + c] : wr[op * 256 + c];
  else          v = pl ?  wr[(op - 256) * 256 + c] : wi[(op - 256) * 256 + c];
  dst[i] = f2b(v);
}
__global__ void k_cbias(const float* __restrict__ br, const float* __restrict__ bi,
                        float* __restrict__ cb) {
  int t = threadIdx.x;
  cb[t] = (t < 256) ? br[t] : bi[t - 256];
}

// ---------------------------------------------------------------- Gr=|G|^2 -> bigT[:,1024+c] bf16
__global__ void k_g2(const u16* __restrict__ G2b, u16* __restrict__ bigT) {
  int i = blockIdx.x * 256 + threadIdx.x;   // 16384*256
  int row = i >> 8, c = i & 255;
  float re = b2f(G2b[(size_t)row * 512 + 2 * c]);
  float im = b2f(G2b[(size_t)row * 512 + 2 * c + 1]);
  bigT[(size_t)row * 1280 + 1024 + c] = f2b(re * re + im * im);
}

// ---------------------------------------------------------------- generic bf16 MFMA GEMM
// D[M][N] = A[M][K] * Bt[N][K]^T  (both bf16, k-contiguous), fp32 accum.
// Staging via global_load_lds width=16 (LDS layout = wave base + lane*16B).
// STATS: per-M-row softmax partials over this block's 128-col tile.
template<int BM, int STATS>
__launch_bounds__(256)
__global__ void k_mm(const u16* __restrict__ Ab, long a_bs, int lda,
                     const u16* __restrict__ Btb, long b_bs, int ldb,
                     int K, int tiles_m, int tiles_n,
                     const float* __restrict__ bias,
                     const float* __restrict__ bng, const float* __restrict__ bnb,
                     const float* __restrict__ cbias,
                     int act,
                     const float* __restrict__ res, long res_bs, int res_sub,
                     float* __restrict__ outF, long outF_bs, int ldF,
                     u16* __restrict__ outB, long outB_bs, int ldBo, int ileave,
                     u16* __restrict__ outT, long outT_bs, int ldT,
                     float* __restrict__ outPool,
                     float* __restrict__ outStats) {
  constexpr int BN = 128;
  constexpr int WM = (BM == 128) ? 64 : 32;
  constexpr int MI = WM / 16;
  __shared__ u16 smem[BN * BM];            // >= As(BM*32)+Bs(BN*32); also T[BN][BM] / reductions
  u16* As = smem;
  u16* Bs = smem + BM * 32;
  int t = threadIdx.x;
  int l = t & 63, w = t >> 6;
  int p = l & 15, q = l >> 4;
  int bid = blockIdx.x;
  int tn = bid % tiles_n;
  int tm = (bid / tiles_n) % tiles_m;
  int b  = bid / (tiles_n * tiles_m);
  int m0 = tm * BM, n0 = tn * BN;
  int wm = w >> 1, wn = w & 1;
  const u16* Ap = Ab + (size_t)b * a_bs;
  const u16* Bp = Btb + (size_t)b * b_bs;

  f4v acc[MI][4];
  #pragma unroll
  for (int i = 0; i < MI; i++)
    #pragma unroll
    for (int j = 0; j < 4; j++) acc[i][j] = (f4v){0.f, 0.f, 0.f, 0.f};

  int arow = t >> 2, kg = (t & 3) * 8;
  for (int k0 = 0; k0 < K; k0 += 32) {
    __syncthreads();
    // As/Bs: LDS byte offset for thread t is it*4096 + t*16 -> wave base + lane*16B
    #pragma unroll
    for (int it = 0; it < BM / 64; it++)
      gld16(As + it * 2048 + w * 512,
            Ap + (size_t)(m0 + it * 64 + arow) * lda + k0 + kg);
    #pragma unroll
    for (int it = 0; it < 2; it++)
      gld16(Bs + it * 2048 + w * 512,
            Bp + (size_t)(n0 + it * 64 + arow) * ldb + k0 + kg);
    __syncthreads();
    s8v af[MI], bf[4];
    #pragma unroll
    for (int i = 0; i < MI; i++)
      af[i] = *(const s8v*)&As[(wm * WM + i * 16 + p) * 32 + q * 8];
    #pragma unroll
    for (int j = 0; j < 4; j++)
      bf[j] = *(const s8v*)&Bs[(wn * 64 + j * 16 + p) * 32 + q * 8];
    #pragma unroll
    for (int i = 0; i < MI; i++)
      #pragma unroll
      for (int j = 0; j < 4; j++)
        acc[i][j] = __builtin_amdgcn_mfma_f32_16x16x32_bf16(af[i], bf[j], acc[i][j], 0, 0, 0);
  }

  __syncthreads();   // LDS reuse (transpose / reductions)

  float cbv[4];
  #pragma unroll
  for (int j = 0; j < 4; j++) {
    int no = n0 + wn * 64 + j * 16 + p;
    cbv[j] = cbias ? cbias[no] : 0.0f;
  }
  float pmax[MI][4];
  #pragma unroll
  for (int i = 0; i < MI; i++)
    #pragma unroll
    for (int r = 0; r < 4; r++) pmax[i][r] = -3.0e38f;
  const float BNS = 0.99999500003749966f;  // 1/sqrt(1+1e-5)
  #pragma unroll
  for (int i = 0; i < MI; i++) {
    #pragma unroll
    for (int r = 0; r < 4; r++) {
      int mo = m0 + wm * WM + i * 16 + q * 4 + r;
      float mult = 1.f, add = 0.f;
      if (bias) add = bias[mo];
      if (bng) { float s = bng[mo] * BNS; add = add * s + bnb[mo]; mult = s; }
      #pragma unroll
      for (int j = 0; j < 4; j++) {
        int no = n0 + wn * 64 + j * 16 + p;
        float v = acc[i][j][r];
        v = v * mult + add;
        if (cbias) v += cbv[j];
        if (act == 1) v = fmaxf(v, 0.f);
        else if (act == 2) v = v > 0.f ? v : 0.2f * v;
        if (res) {
          float rv = res[(size_t)b * res_bs + (size_t)mo * NN + no];
          v = res_sub ? rv - v : rv + v;
        }
        if (outPool) pmax[i][r] = fmaxf(pmax[i][r], v);
        if (outF) outF[(size_t)b * outF_bs + (size_t)mo * ldF + no] = v;
        if (outB) {
          int noo = ileave ? (((no & 255) << 1) | (no >> 8)) : no;
          outB[(size_t)b * outB_bs + (size_t)mo * ldBo + noo] = f2b(v);
        }
        if (outT) smem[(wn * 64 + j * 16 + p) * BM + (mo - m0)] = f2b(v);
      }
    }
  }
  if (outT) {
    __syncthreads();
    constexpr int CPR = BM / 8;            // threads per row (8 bf16 each)
    constexpr int RPP = 256 / CPR;
    int row0 = t / CPR, cg = (t % CPR) * 8;
    for (int rr = row0; rr < BN; rr += RPP) {
      float4 v = *(const float4*)&smem[rr * BM + cg];
      *(float4*)(outT + (size_t)b * outT_bs + (size_t)(n0 + rr) * ldT + m0 + cg) = v;
    }
  }
  if (outPool) {
    float* pf = (float*)smem;              // [BM][2]
    #pragma unroll
    for (int i = 0; i < MI; i++)
      #pragma unroll
      for (int r = 0; r < 4; r++) {
        float m = pmax[i][r];
        #pragma unroll
        for (int o = 1; o < 16; o <<= 1) m = fmaxf(m, __shfl_xor(m, o, 64));
        if (p == 0) pf[(wm * WM + i * 16 + q * 4 + r) * 2 + wn] = m;
      }
    __syncthreads();
    if (t < BM) {
      float mv = fmaxf(pf[t * 2], pf[t * 2 + 1]);
      // coalesced: [b][tn][M] — each block writes BM contiguous floats
      outPool[((size_t)b * tiles_n + tn) * (size_t)(tiles_m * BM) + m0 + t] = mv;
    }
  }
  if (STATS) {
    float* sm1 = (float*)smem;             // [BM][2] max
    float* sm2 = sm1 + BM * 2;             // [BM][2] expsum
    #pragma unroll
    for (int i = 0; i < MI; i++)
      #pragma unroll
      for (int r = 0; r < 4; r++) {
        float m = fmaxf(fmaxf(acc[i][0][r], acc[i][1][r]), fmaxf(acc[i][2][r], acc[i][3][r]));
        #pragma unroll
        for (int o = 1; o < 16; o <<= 1) m = fmaxf(m, __shfl_xor(m, o, 64));
        if (p == 0) sm1[(wm * WM + i * 16 + q * 4 + r) * 2 + wn] = m;
      }
    __syncthreads();
    #pragma unroll
    for (int i = 0; i < MI; i++)
      #pragma unroll
      for (int r = 0; r < 4; r++) {
        int row = wm * WM + i * 16 + q * 4 + r;
        float g = fmaxf(sm1[row * 2], sm1[row * 2 + 1]);
        float s = __expf(acc[i][0][r] - g) + __expf(acc[i][1][r] - g) +
                  __expf(acc[i][2][r] - g) + __expf(acc[i][3][r] - g);
        #pragma unroll
        for (int o = 1; o < 16; o <<= 1) s += __shfl_xor(s, o, 64);
        if (p == 0) sm2[row * 2 + wn] = s;
      }
    __syncthreads();
    if (t < BM) {
      float g = fmaxf(sm1[t * 2], sm1[t * 2 + 1]);
      float ssum = sm2[t * 2] + sm2[t * 2 + 1];
      *(float2*)(outStats + (((size_t)b * (tiles_m * BM) + m0 + t) * tiles_n + tn) * 2)
          = make_float2(g, ssum);
    }
  }
}

// ---------------------------------------------------------------- fused softmax+colsum+xr+diff (E bf16, symmetric)
// c-tile = 64 (grid 512 = 2 blocks/CU).  D[c][m] = sum_n xv[c][n] * p[n][m],
// p[n][m] = exp(E[m][n]-rmax[n])*rinv[n];  rmax/rinv combined from per-tile partials.
// diffT[m][c] = Xin[c][m] - D[c][m] / (1e-9 + colsum[m])
__launch_bounds__(256)
__global__ void k_xratt(const u16* __restrict__ xv_, const u16* __restrict__ E,
                        const float* __restrict__ part_,
                        const float* __restrict__ XinF, long xinF_bs,
                        u16* __restrict__ diffT) {
  __shared__ u16 smem[8192];           // As(0..2047) Bs(2048..6143); reuse: T[128][64]
  __shared__ float colred[128][4];
  __shared__ float rmS[1024];
  __shared__ float riS[1024];
  u16* As = smem;
  u16* Bs = smem + 2048;
  int t = threadIdx.x;
  int l = t & 63, w = t >> 6;
  int p = l & 15, q = l >> 4;
  int bid = blockIdx.x;
  int mt = bid & 7, ct = (bid >> 3) & 3, b = bid >> 5;
  int c0 = ct * 64, m0 = mt * 128;
  int wm = w >> 1, wn = w & 1;
  const u16* Ap = xv_ + (size_t)b * 262144;
  const u16* Ep = E + ((size_t)b << 20);
  // prologue: combine 8 tile-partials per row -> rmax, 1/expsum
  {
    const float2* pbase = (const float2*)(part_ + (size_t)b * 16384);
    for (int row = t; row < 1024; row += 256) {
      const float2* pp = pbase + row * 8;
      float2 vv[8];
      #pragma unroll
      for (int k = 0; k < 8; k++) vv[k] = pp[k];
      float g = vv[0].x;
      #pragma unroll
      for (int k = 1; k < 8; k++) g = fmaxf(g, vv[k].x);
      float s = 0.f;
      #pragma unroll
      for (int k = 0; k < 8; k++) s += vv[k].y * __expf(vv[k].x - g);
      rmS[row] = g;
      riS[row] = 1.0f / s;
    }
  }
  f4v acc[2][4];
  #pragma unroll
  for (int i = 0; i < 2; i++)
    #pragma unroll
    for (int j = 0; j < 4; j++) acc[i][j] = (f4v){0.f, 0.f, 0.f, 0.f};
  float colpart0 = 0.f, colpart1 = 0.f;
  int arow = t >> 2, kg = (t & 3) * 8;
  for (int k0 = 0; k0 < 1024; k0 += 32) {
    __syncthreads();
    gld16(As + w * 512, Ap + (size_t)(c0 + arow) * 1024 + k0 + kg);
    float4 ma0 = *(const float4*)&rmS[k0 + kg];
    float4 ma1 = *(const float4*)&rmS[k0 + kg + 4];
    float4 ia0 = *(const float4*)&riS[k0 + kg];
    float4 ia1 = *(const float4*)&riS[k0 + kg + 4];
    #pragma unroll
    for (int it = 0; it < 2; it++) {
      int r = it * 64 + arow;
      uint4 e8 = *(const uint4*)(Ep + (size_t)(m0 + r) * 1024 + k0 + kg);
      float p0 = __expf(blo(e8.x) - ma0.x) * ia0.x;
      float p1 = __expf(bhi(e8.x) - ma0.y) * ia0.y;
      float p2 = __expf(blo(e8.y) - ma0.z) * ia0.z;
      float p3 = __expf(bhi(e8.y) - ma0.w) * ia0.w;
      float p4 = __expf(blo(e8.z) - ma1.x) * ia1.x;
      float p5 = __expf(bhi(e8.z) - ma1.y) * ia1.y;
      float p6 = __expf(blo(e8.w) - ma1.z) * ia1.z;
      float p7 = __expf(bhi(e8.w) - ma1.w) * ia1.w;
      float s8 = ((p0 + p1) + (p2 + p3)) + ((p4 + p5) + (p6 + p7));
      if (it == 0) colpart0 += s8; else colpart1 += s8;
      uint32 w0 = (uint32)f2b(p0) | ((uint32)f2b(p1) << 16);
      uint32 w1 = (uint32)f2b(p2) | ((uint32)f2b(p3) << 16);
      uint32 w2 = (uint32)f2b(p4) | ((uint32)f2b(p5) << 16);
      uint32 w3 = (uint32)f2b(p6) | ((uint32)f2b(p7) << 16);
      *(uint4*)&Bs[r * 32 + kg] = make_uint4(w0, w1, w2, w3);
    }
    __syncthreads();
    s8v af[2], bf[4];
    #pragma unroll
    for (int i = 0; i < 2; i++)
      af[i] = *(const s8v*)&As[(wm * 32 + i * 16 + p) * 32 + q * 8];
    #pragma unroll
    for (int j = 0; j < 4; j++)
      bf[j] = *(const s8v*)&Bs[(wn * 64 + j * 16 + p) * 32 + q * 8];
    #pragma unroll
    for (int i = 0; i < 2; i++)
      #pragma unroll
      for (int j = 0; j < 4; j++)
        acc[i][j] = __builtin_amdgcn_mfma_f32_16x16x32_bf16(af[i], bf[j], acc[i][j], 0, 0, 0);
  }
  colred[arow][t & 3] = colpart0;
  colred[64 + arow][t & 3] = colpart1;
  __syncthreads();
  float csv[4];
  #pragma unroll
  for (int j = 0; j < 4; j++) {
    int ml = wn * 64 + j * 16 + p;
    csv[j] = 1.0f / (1e-9f + colred[ml][0] + colred[ml][1] + colred[ml][2] + colred[ml][3]);
  }
  #pragma unroll
  for (int i = 0; i < 2; i++) {
    #pragma unroll
    for (int r = 0; r < 4; r++) {
      int cl = wm * 32 + i * 16 + q * 4 + r;
      int c = c0 + cl;
      #pragma unroll
      for (int j = 0; j < 4; j++) {
        int ml = wn * 64 + j * 16 + p;
        float v = acc[i][j][r] * csv[j];
        float rv = XinF[(size_t)b * xinF_bs + (size_t)c * 1024 + m0 + ml];
        smem[ml * 64 + cl] = f2b(rv - v);
      }
    }
  }
  __syncthreads();
  int rr0 = t >> 3, cg = (t & 7) * 8;
  #pragma unroll
  for (int k = 0; k < 4; k++) {
    int rr = rr0 + k * 32;
    *(float4*)(diffT + (size_t)b * 262144 + (size_t)(m0 + rr) * 256 + c0 + cg) =
        *(const float4*)&smem[rr * 64 + cg];
  }
}

// ---------------------------------------------------------------- reduce 8 pool partials ([b][tn][o] layout)
__global__ void k_pool8(const float* __restrict__ pp, float* __restrict__ pool) {
  int i = blockIdx.x * 256 + threadIdx.x;  // b*1024 + o
  int b = i >> 10, o = i & 1023;
  const float* base = pp + (size_t)b * 8192 + o;
  float m = base[0];
  #pragma unroll
  for (int tn = 1; tn < 8; tn++) m = fmaxf(m, base[tn * 1024]);
  pool[i] = m;
}

// ---------------------------------------------------------------- small FC layers fp32
__global__ void k_fc(const float* __restrict__ in, int Cc,
                     const float* __restrict__ W,
                     const float* __restrict__ bias,
                     const float* __restrict__ bng, const float* __restrict__ bnb,
                     int act, float* __restrict__ out, int O) {
  int i = blockIdx.x * 256 + threadIdx.x;
  if (i >= BB * O) return;
  int b = i / O, o = i % O;
  const float* xp = in + (size_t)b * Cc;
  const float* wp = W + (size_t)o * Cc;
  float s = 0.f;
  for (int c = 0; c < Cc; c += 4) {
    float4 xv = *(const float4*)(xp + c);
    float4 wv = *(const float4*)(wp + c);
    s += xv.x * wv.x + xv.y * wv.y + xv.z * wv.z + xv.w * wv.w;
  }
  if (bias) s += bias[o];
  const float BNS = 0.99999500003749966f;
  if (bng) s = s * (bng[o] * BNS) + bnb[o];
  if (act == 2) s = s > 0.f ? s : 0.2f * s;
  else if (act == 1) s = fmaxf(s, 0.f);
  out[i] = s;
}

// ---------------------------------------------------------------- host
extern "C" void kernel_launch(void* const* d_in, const int* in_sizes, int n_in,
                              void* d_out, int out_size, void* d_ws, size_t ws_size,
                              hipStream_t stream) {
  const float* x        = (const float*)d_in[0];
  const float* A        = (const float*)d_in[1];
  const float* P        = (const float*)d_in[2];
  const float* cl1_wr   = (const float*)d_in[3];
  const float* cl1_wi   = (const float*)d_in[4];
  const float* cl1_br   = (const float*)d_in[5];
  const float* cl1_bi   = (const float*)d_in[6];
  const float* cl2_wr   = (const float*)d_in[7];
  const float* cl2_wi   = (const float*)d_in[8];
  const float* cl2_br   = (const float*)d_in[9];
  const float* cl2_bi   = (const float*)d_in[10];
  const float* pt_c1_w  = (const float*)d_in[11];
  const float* pt_c2_w  = (const float*)d_in[12];
  const float* pt_bn1_g = (const float*)d_in[13];
  const float* pt_bn1_b = (const float*)d_in[14];
  const float* pt_bn2_g = (const float*)d_in[15];
  const float* pt_bn2_b = (const float*)d_in[16];
  const float* sa_qk_w  = (const float*)d_in[17];
  const float* sa_v_w   = (const float*)d_in[18];
  const float* sa_v_b   = (const float*)d_in[19];
  const float* sa_t_w   = (const float*)d_in[20];
  const float* sa_t_b   = (const float*)d_in[21];
  const float* sa_bn_g  = (const float*)d_in[22];
  const float* sa_bn_b  = (const float*)d_in[23];
  const float* fuse_w   = (const float*)d_in[24];
  const float* fuse_g   = (const float*)d_in[25];
  const float* fuse_b   = (const float*)d_in[26];
  const float* lin1_w   = (const float*)d_in[27];
  const float* bn6_g    = (const float*)d_in[28];
  const float* bn6_b    = (const float*)d_in[29];
  const float* lin2_w   = (const float*)d_in[30];
  const float* lin2_b   = (const float*)d_in[31];
  const float* bn7_g    = (const float*)d_in[32];
  const float* bn7_b    = (const float*)d_in[33];
  const float* lin3_w   = (const float*)d_in[34];
  const float* lin3_b   = (const float*)d_in[35];

  float* ws = (float*)d_ws;
  // ---- workspace layout (float offsets) ----
  const size_t oPts  = 0;                         // 49152
  const size_t oS    = 65536;                     // 16777216 f scratch (aliased per phase)
  const size_t oBigT = oS + 16777216;             // 10485760 (bf16 [16][1024][1280])
  const size_t oXf0  = oBigT + 10485760;          // 4194304
  const size_t oXf1  = oXf0 + 4194304;            // 4194304
  const size_t oH1T  = oXf1 + 4194304;            // 2097152 (h1T / diffT alias)
  const size_t oH2T  = oH1T + 2097152;            // 2097152
  const size_t oXkT  = oH2T + 2097152;            // 524288
  const size_t oXv   = oXkT + 524288;             // 2097152
  const size_t oAux  = oXv + 2097152;             // 8388608: phase1 eAT+J; phase2 part
  const size_t oGb   = oAux + 8388608;            // 4194304 (bf16 [16384][512])
  const size_t oW1c  = oGb + 4194304;             // 131072
  const size_t oW2c  = oW1c + 131072;             // 131072
  const size_t oCb1  = oW2c + 131072;             // 512
  const size_t oCb2  = oCb1 + 512;                // 512
  const size_t oPool = oCb2 + 512;                // 16384
  const size_t oFc1  = oPool + 16384;             // 8192
  const size_t oFc2  = oFc1 + 8192;               // 4096
  const size_t oWp   = oFc2 + 4096;               // bf16 weight pool

  float*  pts  = ws + oPts;
  // scratch S aliases: phase1 eA|Mj -> G1b|G2b -> Eb (bf16, 32MB); poolP in upper half
  float2* eA   = (float2*)(ws + oS);
  float2* Mj   = (float2*)(ws + oS + 8388608);
  u16*    G1b  = (u16*)(ws + oS);
  u16*    G2b  = (u16*)(ws + oS + 8388608);
  u16*    Eb   = (u16*)(ws + oS);                 // bf16 [16][1024][1024] = 8388608 f
  float*  poolP= ws + oS + 8388608;               // [16][8][1024]
  u16*    bigT = (u16*)(ws + oBigT);
  float*  Xf0  = ws + oXf0;
  float*  Xf1  = ws + oXf1;
  u16*    h1T  = (u16*)(ws + oH1T);
  u16*    diffT= (u16*)(ws + oH1T);
  u16*    h2T  = (u16*)(ws + oH2T);
  u16*    xkT  = (u16*)(ws + oXkT);
  u16*    xv   = (u16*)(ws + oXv);
  u16*    eAT  = (u16*)(ws + oAux);               // phase1
  u16*    Jb   = (u16*)(ws + oAux + 4194304);     // phase1
  float*  partP= ws + oAux;                       // phase2 (eAT dead): [16][1024][8][2]
  u16*    Gb   = (u16*)(ws + oGb);
  u16*    W1c  = (u16*)(ws + oW1c);
  u16*    W2c  = (u16*)(ws + oW2c);
  float*  cb1  = ws + oCb1;
  float*  cb2  = ws + oCb2;
  float*  pool = ws + oPool;
  float*  fc1  = ws + oFc1;
  float*  fc2  = ws + oFc2;
  u16*    wp   = (u16*)(ws + oWp);
  u16* wp_pt1  = wp;
  u16* wp_pt2  = wp + 65536;
  u16* wp_qk   = wp + 131072;
  u16* wp_v    = wp + 196608;
  u16* wp_t    = wp + 458752;
  u16* wp_fuse = wp + 720896;

  // ---- weight prep ----
  k_cast<<<256, 256, 0, stream>>>(pt_c1_w, wp_pt1, 65536);
  k_cast<<<256, 256, 0, stream>>>(pt_c2_w, wp_pt2, 65536);
  k_cast<<<256, 256, 0, stream>>>(sa_qk_w, wp_qk, 65536);
  k_cast<<<1024, 256, 0, stream>>>(sa_v_w, wp_v, 262144);
  k_cast<<<1024, 256, 0, stream>>>(sa_t_w, wp_t, 262144);
  k_cast<<<5120, 256, 0, stream>>>(fuse_w, wp_fuse, 1310720);
  k_wprep<<<1024, 256, 0, stream>>>(cl1_wr, cl1_wi, W1c);
  k_wprep<<<1024, 256, 0, stream>>>(cl2_wr, cl2_wi, W2c);
  k_cbias<<<1, 512, 0, stream>>>(cl1_br, cl1_bi, cb1);
  k_cbias<<<1, 512, 0, stream>>>(cl2_br, cl2_bi, cb2);

  // ---- VecKM: M = J @ eA via MFMA ----
  k_pts<<<64, 256, 0, stream>>>(x, pts);
  k_phase<<<16384, 256, 0, stream>>>(pts, A, eA);
  k_eat<<<2048, 256, 0, stream>>>(eA, eAT);
  k_jbuild<<<16384, 256, 0, stream>>>(pts, Jb);
  k_mm<128,0><<<512, 256, 0, stream>>>(Jb, 1048576, 1024, eAT, 524288, 1024, 1024, 8, 4,
      nullptr, nullptr, nullptr, nullptr, 0, nullptr, 0, 0,
      (float*)Mj, 524288, 512, nullptr, 0, 0, 0, nullptr, 0, 0, nullptr, nullptr);
  k_norm<<<BB * NN, 256, 0, stream>>>(Mj, eA, pts, P, Gb);

  // ---- complex linears as single real MFMA GEMMs (K=512) ----
  k_mm<128,0><<<512, 256, 0, stream>>>(Gb, 0, 512, W1c, 0, 512, 512, 128, 4,
      nullptr, nullptr, nullptr, cb1, 1, nullptr, 0, 0,
      nullptr, 0, 0, G1b, 0, 512, 1, nullptr, 0, 0, nullptr, nullptr);
  k_mm<128,0><<<512, 256, 0, stream>>>(G1b, 0, 512, W2c, 0, 512, 512, 128, 4,
      nullptr, nullptr, nullptr, cb2, 0, nullptr, 0, 0,
      nullptr, 0, 0, G2b, 0, 512, 1, nullptr, 0, 0, nullptr, nullptr);
  k_g2<<<16384, 256, 0, stream>>>(G2b, bigT);

  const long bsBigT = 1310720;   // ushort units
  const long bsH256 = 262144;
  const long bsXkT  = 65536;
  const long bsXvU  = 262144;
  const long bsF    = 262144;
  const long bsEU   = 1048576;   // Eb bf16 [1024][1024]

  // ---- pt convs (BM=64 -> 512 blocks, 2/CU) ----
  k_mm<64,0><<<512, 256, 0, stream>>>(wp_pt1, 0, 256, bigT + 1024, bsBigT, 1280, 256, 4, 8,
      nullptr, pt_bn1_g, pt_bn1_b, nullptr, 1, nullptr, 0, 0,
      nullptr, 0, 0, nullptr, 0, 0, 0, h1T, bsH256, 256, nullptr, nullptr);
  k_mm<64,0><<<512, 256, 0, stream>>>(wp_pt2, 0, 256, h1T, bsH256, 256, 256, 4, 8,
      nullptr, pt_bn2_g, pt_bn2_b, nullptr, 1, nullptr, 0, 0,
      Xf0, bsF, 1024, nullptr, 0, 0, 0, h2T, bsH256, 256, nullptr, nullptr);

  // ---- 4 SA layers (materialized bf16 E, stats fused into energy GEMM) ----
  for (int i = 0; i < 4; i++) {
    const u16* XinT   = (i == 0) ? h2T : (bigT + (i - 1) * 256);
    long       xinT_bs= (i == 0) ? bsH256 : bsBigT;
    int        xinT_ld= (i == 0) ? 256 : 1280;
    float*     XinF   = (i & 1) ? Xf1 : Xf0;
    float*     XoutF  = (i & 1) ? Xf0 : Xf1;
    const u16* qkw = wp_qk + (size_t)i * 16384;
    const u16* vw  = wp_v + (size_t)i * 65536;
    const u16* tw  = wp_t + (size_t)i * 65536;

    // qk conv: [64][256] -> xkT bf16 [n][64]
    k_mm<64,0><<<128, 256, 0, stream>>>(qkw, 0, 256, XinT, xinT_bs, xinT_ld, 256, 1, 8,
        nullptr, nullptr, nullptr, nullptr, 0, nullptr, 0, 0,
        nullptr, 0, 0, nullptr, 0, 0, 0, xkT, bsXkT, 64, nullptr, nullptr);
    // v conv (BM=64 -> 512 blocks): -> xv bf16 [c][n] (+bias)
    k_mm<64,0><<<512, 256, 0, stream>>>(vw, 0, 256, XinT, xinT_bs, xinT_ld, 256, 4, 8,
        sa_v_b + i * 256, nullptr, nullptr, nullptr, 0, nullptr, 0, 0,
        nullptr, 0, 0, xv, bsXvU, 1024, 0, nullptr, 0, 0, nullptr, nullptr);
    // energy E = xkT * xkT^T -> bf16 [n][m] + fused per-tile softmax stats
    k_mm<128,1><<<1024, 256, 0, stream>>>(xkT, bsXkT, 64, xkT, bsXkT, 64, 64, 8, 8,
        nullptr, nullptr, nullptr, nullptr, 0, nullptr, 0, 0,
        nullptr, 0, 0, Eb, bsEU, 1024, 0, nullptr, 0, 0, nullptr, partP);
    k_xratt<<<512, 256, 0, stream>>>(xv, Eb, partP, XinF, bsF, diffT);
    // t conv (BM=64 -> 512 blocks): relu(bn(tw@diff + tb)) + Xin -> XoutF fp32 + bigT slice bf16
    k_mm<64,0><<<512, 256, 0, stream>>>(tw, 0, 256, diffT, bsH256, 256, 256, 4, 8,
        sa_t_b + i * 256, sa_bn_g + i * 256, sa_bn_b + i * 256, nullptr, 1,
        XinF, bsF, 0,
        XoutF, bsF, 1024, nullptr, 0, 0, 0, bigT + i * 256, bsBigT, 1280, nullptr, nullptr);
  }

  // ---- fuse conv with fused max pool (coalesced partials) ----
  k_mm<128,0><<<1024, 256, 0, stream>>>(wp_fuse, 0, 1280, bigT, bsBigT, 1280, 1280, 8, 8,
      nullptr, fuse_g, fuse_b, nullptr, 2, nullptr, 0, 0,
      nullptr, 0, 0, nullptr, 0, 0, 0, nullptr, 0, 0, poolP, nullptr);
  k_pool8<<<64, 256, 0, stream>>>(poolP, pool);

  // ---- MLP head ----
  k_fc<<<32, 256, 0, stream>>>(pool, 1024, lin1_w, nullptr, bn6_g, bn6_b, 2, fc1, 512);
  k_fc<<<16, 256, 0, stream>>>(fc1, 512, lin2_w, lin2_b, bn7_g, bn7_b, 2, fc2, 256);
  k_fc<<<3, 256, 0, stream>>>(fc2, 256, lin3_w, lin3_b, nullptr, nullptr, 0, (float*)d_out, 40);
}

// Round 9
// 1015.156 us; speedup vs baseline: 1.0972x; 1.0972x over previous
//
#include <hip/hip_runtime.h>
#include <math.h>

#define BB 16
#define NN 1024
#define DD 256

typedef unsigned short u16;
typedef unsigned int uint32;
typedef __attribute__((ext_vector_type(8))) short s8v;   // 8 bf16 (4 VGPRs)
typedef __attribute__((ext_vector_type(4))) float f4v;   // 4 fp32 acc

__device__ __forceinline__ u16 f2b(float f) {            // RNE fp32->bf16
  uint32 u = __float_as_uint(f);
  return (u16)((u + 0x7fffu + ((u >> 16) & 1u)) >> 16);
}
__device__ __forceinline__ float b2f(u16 u) {
  return __uint_as_float(((uint32)u) << 16);
}
__device__ __forceinline__ float blo(uint32 w) { return __uint_as_float(w << 16); }
__device__ __forceinline__ float bhi(uint32 w) { return __uint_as_float(w & 0xffff0000u); }

// async global->LDS DMA, 16B per lane; lds base must be wave-uniform (HW scatters +lane*16B)
__device__ __forceinline__ void gld16(u16* lds, const u16* g) {
  __builtin_amdgcn_global_load_lds(
      (const __attribute__((address_space(1))) unsigned int*)g,
      (__attribute__((address_space(3))) unsigned int*)lds, 16, 0, 0);
}

__device__ __forceinline__ float waveRedSum(float v) {
  #pragma unroll
  for (int o = 32; o; o >>= 1) v += __shfl_xor(v, o, 64);
  return v;
}
__device__ __forceinline__ float waveRedMax(float v) {
  #pragma unroll
  for (int o = 32; o; o >>= 1) v = fmaxf(v, __shfl_xor(v, o, 64));
  return v;
}

// ---------------------------------------------------------------- merged prep: pts + all weight casts
// regions (element index space):
//  [0,16384)            pts          (per bn)
//  [16384,81920)        pt1 cast
//  [81920,147456)       pt2 cast
//  [147456,475136)      qkv stacked cast: 4 layers x [320][256]
//  [475136,737280)      t cast
//  [737280,2048000)     fuse cast
//  [2048000,2310144)    W1 complex prep
//  [2310144,2572288)    W2 complex prep
//  [2572288,2572800)    cb1
//  [2572800,2573312)    cb2
__global__ void k_prep(const float* __restrict__ x, float* __restrict__ pts,
                       const float* __restrict__ pt1w, const float* __restrict__ pt2w,
                       const float* __restrict__ qkw, const float* __restrict__ vw,
                       const float* __restrict__ tw, const float* __restrict__ fw,
                       const float* __restrict__ w1r, const float* __restrict__ w1i,
                       const float* __restrict__ w2r, const float* __restrict__ w2i,
                       const float* __restrict__ b1r, const float* __restrict__ b1i,
                       const float* __restrict__ b2r, const float* __restrict__ b2i,
                       u16* __restrict__ wp_pt1, u16* __restrict__ wp_pt2,
                       u16* __restrict__ wp_qkv, u16* __restrict__ wp_t,
                       u16* __restrict__ wp_fuse,
                       u16* __restrict__ W1c, u16* __restrict__ W2c,
                       float* __restrict__ cb1, float* __restrict__ cb2) {
  int i = blockIdx.x * 256 + threadIdx.x;
  if (i < 16384) {
    int b = i >> 10, n = i & 1023;
    const float* xb = x + (size_t)b * 3072;
    pts[i * 3 + 0] = xb[n];
    pts[i * 3 + 1] = xb[1024 + n];
    pts[i * 3 + 2] = xb[2048 + n];
  } else if (i < 81920) {
    int k = i - 16384;  wp_pt1[k] = f2b(pt1w[k]);
  } else if (i < 147456) {
    int k = i - 81920;  wp_pt2[k] = f2b(pt2w[k]);
  } else if (i < 475136) {
    int k = i - 147456;
    int layer = k / 81920, rem = k % 81920;
    int r = rem >> 8, c = rem & 255;
    float v = (r < 64) ? qkw[layer * 16384 + r * 256 + c]
                       : vw[layer * 65536 + (r - 64) * 256 + c];
    wp_qkv[k] = f2b(v);
  } else if (i < 737280) {
    int k = i - 475136; wp_t[k] = f2b(tw[k]);
  } else if (i < 2048000) {
    int k = i - 737280; wp_fuse[k] = f2b(fw[k]);
  } else if (i < 2310144) {
    int k = i - 2048000;
    int op = k >> 9, c2 = k & 511, c = c2 >> 1, pl = c2 & 1;
    float v;
    if (op < 256) v = pl ? -w1i[op * 256 + c] : w1r[op * 256 + c];
    else          v = pl ?  w1r[(op - 256) * 256 + c] : w1i[(op - 256) * 256 + c];
    W1c[k] = f2b(v);
  } else if (i < 2572288) {
    int k = i - 2310144;
    int op = k >> 9, c2 = k & 511, c = c2 >> 1, pl = c2 & 1;
    float v;
    if (op < 256) v = pl ? -w2i[op * 256 + c] : w2r[op * 256 + c];
    else          v = pl ?  w2r[(op - 256) * 256 + c] : w2i[(op - 256) * 256 + c];
    W2c[k] = f2b(v);
  } else if (i < 2572800) {
    int k = i - 2572288; cb1[k] = (k < 256) ? b1r[k] : b1i[k - 256];
  } else if (i < 2573312) {
    int k = i - 2572800; cb2[k] = (k < 256) ? b2r[k] : b2i[k - 256];
  }
}

// ---------------------------------------------------------------- eA fp32 [bn][256] float2
__global__ void k_phase(const float* __restrict__ pts, const float* __restrict__ A,
                        float2* __restrict__ eA) {
  int i = blockIdx.x * 256 + threadIdx.x;            // (b*N+n)*256 + d
  int d = i & 255; int bn = i >> 8;
  float p0 = pts[bn * 3], p1 = pts[bn * 3 + 1], p2 = pts[bn * 3 + 2];
  float ta = p0 * A[d] + p1 * A[256 + d] + p2 * A[512 + d];
  float s, c;
  sincosf(ta, &s, &c); eA[i] = make_float2(c, s);
}

// ---------------------------------------------------------------- eA -> eAT bf16 [b][512][1024]
__global__ void k_eat(const float2* __restrict__ eA, u16* __restrict__ eAT) {
  int bid = blockIdx.x;
  int dt = bid & 7, nt = (bid >> 3) & 15, b = bid >> 7;
  int d0 = dt * 32, n0 = nt * 64;
  __shared__ u16 cosT[32][72], sinT[32][72];
  int t = threadIdx.x;
  {
    int n = t >> 2, dg = (t & 3) * 8;
    const float2* p = eA + ((size_t)(b * 1024 + n0 + n)) * 256 + d0 + dg;
    #pragma unroll
    for (int j = 0; j < 8; j++) {
      float2 v = p[j];
      cosT[dg + j][n] = f2b(v.x);
      sinT[dg + j][n] = f2b(v.y);
    }
  }
  __syncthreads();
  {
    int rr = t >> 2, ng = (t & 3) * 16;
    int d = rr >> 1, cmp = rr & 1;
    const u16* src = (cmp ? &sinT[d][ng] : &cosT[d][ng]);
    uint4 v0 = *(const uint4*)src;
    uint4 v1 = *(const uint4*)(src + 8);
    u16* dst = eAT + ((size_t)(b * 512 + 2 * d0 + rr)) * 1024 + n0 + ng;
    *(uint4*)dst = v0;
    *(uint4*)(dst + 8) = v1;
  }
}

// ---------------------------------------------------------------- J bf16 [b][n][1024]
__global__ void k_jbuild(const float* __restrict__ pts, u16* __restrict__ J) {
  int bid = blockIdx.x;                 // b*1024 + n
  int b = bid >> 10, n = bid & 1023;
  int t = threadIdx.x;
  const float* pb = pts + (size_t)b * 3072;
  float pnx = pb[n * 3], pny = pb[n * 3 + 1], pnz = pb[n * 3 + 2];
  int m = t * 4;
  const float* pm = pb + (size_t)m * 3;
  float4 a = *(const float4*)pm;
  float4 bq = *(const float4*)(pm + 4);
  float4 c = *(const float4*)(pm + 8);
  float dx, dy, dz, d2;
  dx = a.x - pnx;  dy = a.y - pny;  dz = a.z - pnz;  d2 = dx*dx + dy*dy + dz*dz;
  float j0 = __expf(-18.0f * d2);
  dx = a.w - pnx;  dy = bq.x - pny; dz = bq.y - pnz; d2 = dx*dx + dy*dy + dz*dz;
  float j1 = __expf(-18.0f * d2);
  dx = bq.z - pnx; dy = bq.w - pny; dz = c.x - pnz;  d2 = dx*dx + dy*dy + dz*dz;
  float j2 = __expf(-18.0f * d2);
  dx = c.y - pnx;  dy = c.z - pny;  dz = c.w - pnz;  d2 = dx*dx + dy*dy + dz*dz;
  float j3 = __expf(-18.0f * d2);
  uint32 lo = (uint32)f2b(j0) | ((uint32)f2b(j1) << 16);
  uint32 hi = (uint32)f2b(j2) | ((uint32)f2b(j3) << 16);
  *(uint2*)(J + (size_t)bid * 1024 + m) = make_uint2(lo, hi);
}

// ------------------------------------------ G = norm(M*conj(eA))*16 + exp(i pts@P) -> interleaved bf16 [bn][512]
__global__ void k_norm(const float2* __restrict__ M, const float2* __restrict__ eA,
                       const float* __restrict__ pts, const float* __restrict__ P,
                       u16* __restrict__ Gb) {
  int bn = blockIdx.x; int c = threadIdx.x;
  size_t idx = (size_t)bn * DD + c;
  float2 m = M[idx], e = eA[idx];
  float gr = m.x * e.x + m.y * e.y;
  float gi = m.y * e.x - m.x * e.y;
  float s = gr * gr + gi * gi;
  s = waveRedSum(s);
  __shared__ float red[4];
  if ((c & 63) == 0) red[c >> 6] = s;
  __syncthreads();
  float tot = red[0] + red[1] + red[2] + red[3];
  float scale = 16.0f / sqrtf(tot);
  float p0 = pts[bn * 3], p1 = pts[bn * 3 + 1], p2 = pts[bn * 3 + 2];
  float tp = p0 * P[c] + p1 * P[256 + c] + p2 * P[512 + c];
  float sp, cp; sincosf(tp, &sp, &cp);
  uint32 pk = (uint32)f2b(gr * scale + cp) | ((uint32)f2b(gi * scale + sp) << 16);
  *(uint32*)(Gb + idx * 2) = pk;
}

// ---------------------------------------------------------------- Gr=|G|^2 -> bigT[:,1024+c] bf16
__global__ void k_g2(const u16* __restrict__ G2b, u16* __restrict__ bigT) {
  int i = blockIdx.x * 256 + threadIdx.x;   // 16384*256
  int row = i >> 8, c = i & 255;
  float re = b2f(G2b[(size_t)row * 512 + 2 * c]);
  float im = b2f(G2b[(size_t)row * 512 + 2 * c + 1]);
  bigT[(size_t)row * 1280 + 1024 + c] = f2b(re * re + im * im);
}

// ---------------------------------------------------------------- generic bf16 MFMA GEMM
// D[M][N] = A[M][K] * Bt[N][K]^T  (both bf16, k-contiguous), fp32 accum.
// Staging via global_load_lds width=16 (LDS layout = wave base + lane*16B).
// STATS: per-M-row softmax partials over this block's 128-col tile.
// QKV: tile tm==0 -> outT (xkT); tiles tm>0 -> outB (xv) with bias[mo-64].
template<int BM, int STATS, int QKV>
__launch_bounds__(256)
__global__ void k_mm(const u16* __restrict__ Ab, long a_bs, int lda,
                     const u16* __restrict__ Btb, long b_bs, int ldb,
                     int K, int tiles_m, int tiles_n,
                     const float* __restrict__ bias,
                     const float* __restrict__ bng, const float* __restrict__ bnb,
                     const float* __restrict__ cbias,
                     int act,
                     const float* __restrict__ res, long res_bs, int res_sub,
                     float* __restrict__ outF, long outF_bs, int ldF,
                     u16* __restrict__ outB, long outB_bs, int ldBo, int ileave,
                     u16* __restrict__ outT, long outT_bs, int ldT,
                     float* __restrict__ outPool,
                     float* __restrict__ outStats) {
  constexpr int BN = 128;
  constexpr int WM = (BM == 128) ? 64 : 32;
  constexpr int MI = WM / 16;
  __shared__ u16 smem[BN * BM];            // >= As(BM*32)+Bs(BN*32); also T[BN][BM] / reductions
  u16* As = smem;
  u16* Bs = smem + BM * 32;
  int t = threadIdx.x;
  int l = t & 63, w = t >> 6;
  int p = l & 15, q = l >> 4;
  int bid = blockIdx.x;
  int tn = bid % tiles_n;
  int tm = (bid / tiles_n) % tiles_m;
  int b  = bid / (tiles_n * tiles_m);
  int m0 = tm * BM, n0 = tn * BN;
  int wm = w >> 1, wn = w & 1;
  const u16* Ap = Ab + (size_t)b * a_bs;
  const u16* Bp = Btb + (size_t)b * b_bs;

  f4v acc[MI][4];
  #pragma unroll
  for (int i = 0; i < MI; i++)
    #pragma unroll
    for (int j = 0; j < 4; j++) acc[i][j] = (f4v){0.f, 0.f, 0.f, 0.f};

  int arow = t >> 2, kg = (t & 3) * 8;
  for (int k0 = 0; k0 < K; k0 += 32) {
    __syncthreads();
    #pragma unroll
    for (int it = 0; it < BM / 64; it++)
      gld16(As + it * 2048 + w * 512,
            Ap + (size_t)(m0 + it * 64 + arow) * lda + k0 + kg);
    #pragma unroll
    for (int it = 0; it < 2; it++)
      gld16(Bs + it * 2048 + w * 512,
            Bp + (size_t)(n0 + it * 64 + arow) * ldb + k0 + kg);
    __syncthreads();
    s8v af[MI], bf[4];
    #pragma unroll
    for (int i = 0; i < MI; i++)
      af[i] = *(const s8v*)&As[(wm * WM + i * 16 + p) * 32 + q * 8];
    #pragma unroll
    for (int j = 0; j < 4; j++)
      bf[j] = *(const s8v*)&Bs[(wn * 64 + j * 16 + p) * 32 + q * 8];
    #pragma unroll
    for (int i = 0; i < MI; i++)
      #pragma unroll
      for (int j = 0; j < 4; j++)
        acc[i][j] = __builtin_amdgcn_mfma_f32_16x16x32_bf16(af[i], bf[j], acc[i][j], 0, 0, 0);
  }

  __syncthreads();   // LDS reuse (transpose / reductions)

  u16* oB = outB;
  u16* oT = outT;
  if (QKV) { if (tm == 0) oB = nullptr; else oT = nullptr; }

  float cbv[4];
  #pragma unroll
  for (int j = 0; j < 4; j++) {
    int no = n0 + wn * 64 + j * 16 + p;
    cbv[j] = cbias ? cbias[no] : 0.0f;
  }
  float pmax[MI][4];
  #pragma unroll
  for (int i = 0; i < MI; i++)
    #pragma unroll
    for (int r = 0; r < 4; r++) pmax[i][r] = -3.0e38f;
  const float BNS = 0.99999500003749966f;  // 1/sqrt(1+1e-5)
  #pragma unroll
  for (int i = 0; i < MI; i++) {
    #pragma unroll
    for (int r = 0; r < 4; r++) {
      int mo = m0 + wm * WM + i * 16 + q * 4 + r;
      float mult = 1.f, add = 0.f;
      if (QKV) {
        if (tm > 0 && bias) add = bias[mo - 64];
      } else {
        if (bias) add = bias[mo];
        if (bng) { float s = bng[mo] * BNS; add = add * s + bnb[mo]; mult = s; }
      }
      #pragma unroll
      for (int j = 0; j < 4; j++) {
        int no = n0 + wn * 64 + j * 16 + p;
        float v = acc[i][j][r];
        v = v * mult + add;
        if (cbias) v += cbv[j];
        if (act == 1) v = fmaxf(v, 0.f);
        else if (act == 2) v = v > 0.f ? v : 0.2f * v;
        if (res) {
          float rv = res[(size_t)b * res_bs + (size_t)mo * NN + no];
          v = res_sub ? rv - v : rv + v;
        }
        if (outPool) pmax[i][r] = fmaxf(pmax[i][r], v);
        if (outF) outF[(size_t)b * outF_bs + (size_t)mo * ldF + no] = v;
        if (oB) {
          int moB = QKV ? (mo - 64) : mo;
          int noo = ileave ? (((no & 255) << 1) | (no >> 8)) : no;
          oB[(size_t)b * outB_bs + (size_t)moB * ldBo + noo] = f2b(v);
        }
        if (oT) smem[(wn * 64 + j * 16 + p) * BM + (mo - m0)] = f2b(v);
      }
    }
  }
  if (oT) {
    __syncthreads();
    constexpr int CPR = BM / 8;            // threads per row (8 bf16 each)
    constexpr int RPP = 256 / CPR;
    int row0 = t / CPR, cg = (t % CPR) * 8;
    for (int rr = row0; rr < BN; rr += RPP) {
      float4 v = *(const float4*)&smem[rr * BM + cg];
      *(float4*)(oT + (size_t)b * outT_bs + (size_t)(n0 + rr) * ldT + m0 + cg) = v;
    }
  }
  if (outPool) {
    float* pf = (float*)smem;              // [BM][2]
    #pragma unroll
    for (int i = 0; i < MI; i++)
      #pragma unroll
      for (int r = 0; r < 4; r++) {
        float m = pmax[i][r];
        #pragma unroll
        for (int o = 1; o < 16; o <<= 1) m = fmaxf(m, __shfl_xor(m, o, 64));
        if (p == 0) pf[(wm * WM + i * 16 + q * 4 + r) * 2 + wn] = m;
      }
    __syncthreads();
    if (t < BM) {
      float mv = fmaxf(pf[t * 2], pf[t * 2 + 1]);
      outPool[((size_t)b * tiles_n + tn) * (size_t)(tiles_m * BM) + m0 + t] = mv;
    }
  }
  if (STATS) {
    float* sm1 = (float*)smem;             // [BM][2] max
    float* sm2 = sm1 + BM * 2;             // [BM][2] expsum
    #pragma unroll
    for (int i = 0; i < MI; i++)
      #pragma unroll
      for (int r = 0; r < 4; r++) {
        float m = fmaxf(fmaxf(acc[i][0][r], acc[i][1][r]), fmaxf(acc[i][2][r], acc[i][3][r]));
        #pragma unroll
        for (int o = 1; o < 16; o <<= 1) m = fmaxf(m, __shfl_xor(m, o, 64));
        if (p == 0) sm1[(wm * WM + i * 16 + q * 4 + r) * 2 + wn] = m;
      }
    __syncthreads();
    #pragma unroll
    for (int i = 0; i < MI; i++)
      #pragma unroll
      for (int r = 0; r < 4; r++) {
        int row = wm * WM + i * 16 + q * 4 + r;
        float g = fmaxf(sm1[row * 2], sm1[row * 2 + 1]);
        float s = __expf(acc[i][0][r] - g) + __expf(acc[i][1][r] - g) +
                  __expf(acc[i][2][r] - g) + __expf(acc[i][3][r] - g);
        #pragma unroll
        for (int o = 1; o < 16; o <<= 1) s += __shfl_xor(s, o, 64);
        if (p == 0) sm2[row * 2 + wn] = s;
      }
    __syncthreads();
    if (t < BM) {
      float g = fmaxf(sm1[t * 2], sm1[t * 2 + 1]);
      float ssum = sm2[t * 2] + sm2[t * 2 + 1];
      *(float2*)(outStats + (((size_t)b * (tiles_m * BM) + m0 + t) * tiles_n + tn) * 2)
          = make_float2(g, ssum);
    }
  }
}

// ---------------------------------------------------------------- fused softmax+colsum+xr+diff (E bf16, symmetric)
// D[c][m] = sum_n xv[c][n] * p[n][m],  p[n][m] = exp(E[m][n]-rmax[n])*rinv[n]
// rmax/rinv combined from per-tile partials in prologue (LDS).
// diffT[m][c] = Xin[c][m] - D[c][m] / (1e-9 + colsum[m])
__launch_bounds__(256)
__global__ void k_xratt(const u16* __restrict__ xv_, const u16* __restrict__ E,
                        const float* __restrict__ part_,
                        const float* __restrict__ XinF, long xinF_bs,
                        u16* __restrict__ diffT) {
  __shared__ u16 smem[16384];          // As(0..4095) Bs(4096..8191); reuse: 128x128 transpose
  __shared__ float colred[128][4];
  __shared__ float rmS[1024];
  __shared__ float riS[1024];
  u16* As = smem;
  u16* Bs = smem + 4096;
  int t = threadIdx.x;
  int l = t & 63, w = t >> 6;
  int p = l & 15, q = l >> 4;
  int bid = blockIdx.x;
  int mt = bid & 7, ct = (bid >> 3) & 1, b = bid >> 4;
  int c0 = ct * 128, m0 = mt * 128;
  int wm = w >> 1, wn = w & 1;
  const u16* Ap = xv_ + (size_t)b * 262144;
  const u16* Ep = E + ((size_t)b << 20);
  // prologue: combine 8 tile-partials per row -> rmax, 1/expsum
  {
    const float2* pbase = (const float2*)(part_ + (size_t)b * 16384);
    for (int row = t; row < 1024; row += 256) {
      const float2* pp = pbase + row * 8;
      float2 vv[8];
      #pragma unroll
      for (int k = 0; k < 8; k++) vv[k] = pp[k];
      float g = vv[0].x;
      #pragma unroll
      for (int k = 1; k < 8; k++) g = fmaxf(g, vv[k].x);
      float s = 0.f;
      #pragma unroll
      for (int k = 0; k < 8; k++) s += vv[k].y * __expf(vv[k].x - g);
      rmS[row] = g;
      riS[row] = 1.0f / s;
    }
  }
  f4v acc[4][4];
  #pragma unroll
  for (int i = 0; i < 4; i++)
    #pragma unroll
    for (int j = 0; j < 4; j++) acc[i][j] = (f4v){0.f, 0.f, 0.f, 0.f};
  float colpart0 = 0.f, colpart1 = 0.f;
  int arow = t >> 2, kg = (t & 3) * 8;
  for (int k0 = 0; k0 < 1024; k0 += 32) {
    __syncthreads();
    #pragma unroll
    for (int it = 0; it < 2; it++)
      gld16(As + it * 2048 + w * 512,
            Ap + (size_t)(c0 + it * 64 + arow) * 1024 + k0 + kg);
    float4 ma0 = *(const float4*)&rmS[k0 + kg];
    float4 ma1 = *(const float4*)&rmS[k0 + kg + 4];
    float4 ia0 = *(const float4*)&riS[k0 + kg];
    float4 ia1 = *(const float4*)&riS[k0 + kg + 4];
    #pragma unroll
    for (int it = 0; it < 2; it++) {
      int r = it * 64 + arow;
      uint4 e8 = *(const uint4*)(Ep + (size_t)(m0 + r) * 1024 + k0 + kg);
      float p0 = __expf(blo(e8.x) - ma0.x) * ia0.x;
      float p1 = __expf(bhi(e8.x) - ma0.y) * ia0.y;
      float p2 = __expf(blo(e8.y) - ma0.z) * ia0.z;
      float p3 = __expf(bhi(e8.y) - ma0.w) * ia0.w;
      float p4 = __expf(blo(e8.z) - ma1.x) * ia1.x;
      float p5 = __expf(bhi(e8.z) - ma1.y) * ia1.y;
      float p6 = __expf(blo(e8.w) - ma1.z) * ia1.z;
      float p7 = __expf(bhi(e8.w) - ma1.w) * ia1.w;
      float s8 = ((p0 + p1) + (p2 + p3)) + ((p4 + p5) + (p6 + p7));
      if (it == 0) colpart0 += s8; else colpart1 += s8;
      uint32 w0 = (uint32)f2b(p0) | ((uint32)f2b(p1) << 16);
      uint32 w1 = (uint32)f2b(p2) | ((uint32)f2b(p3) << 16);
      uint32 w2 = (uint32)f2b(p4) | ((uint32)f2b(p5) << 16);
      uint32 w3 = (uint32)f2b(p6) | ((uint32)f2b(p7) << 16);
      *(uint4*)&Bs[r * 32 + kg] = make_uint4(w0, w1, w2, w3);
    }
    __syncthreads();
    s8v af[4], bf[4];
    #pragma unroll
    for (int i = 0; i < 4; i++)
      af[i] = *(const s8v*)&As[(wm * 64 + i * 16 + p) * 32 + q * 8];
    #pragma unroll
    for (int j = 0; j < 4; j++)
      bf[j] = *(const s8v*)&Bs[(wn * 64 + j * 16 + p) * 32 + q * 8];
    #pragma unroll
    for (int i = 0; i < 4; i++)
      #pragma unroll
      for (int j = 0; j < 4; j++)
        acc[i][j] = __builtin_amdgcn_mfma_f32_16x16x32_bf16(af[i], bf[j], acc[i][j], 0, 0, 0);
  }
  colred[arow][t & 3] = colpart0;
  colred[64 + arow][t & 3] = colpart1;
  __syncthreads();
  float csv[4];
  #pragma unroll
  for (int j = 0; j < 4; j++) {
    int ml = wn * 64 + j * 16 + p;
    csv[j] = 1.0f / (1e-9f + colred[ml][0] + colred[ml][1] + colred[ml][2] + colred[ml][3]);
  }
  #pragma unroll
  for (int i = 0; i < 4; i++) {
    #pragma unroll
    for (int r = 0; r < 4; r++) {
      int cl = wm * 64 + i * 16 + q * 4 + r;
      int c = c0 + cl;
      #pragma unroll
      for (int j = 0; j < 4; j++) {
        int ml = wn * 64 + j * 16 + p;
        float v = acc[i][j][r] * csv[j];
        float rv = XinF[(size_t)b * xinF_bs + (size_t)c * 1024 + m0 + ml];
        smem[ml * 128 + cl] = f2b(rv - v);
      }
    }
  }
  __syncthreads();
  int rr0 = t >> 4, cg = (t & 15) * 8;
  #pragma unroll
  for (int k = 0; k < 8; k++) {
    int rr = rr0 + k * 16;
    *(float4*)(diffT + (size_t)b * 262144 + (size_t)(m0 + rr) * 256 + c0 + cg) =
        *(const float4*)&smem[rr * 128 + cg];
  }
}

// ---------------------------------------------------------------- reduce 8 pool partials ([b][tn][o] layout)
__global__ void k_pool8(const float* __restrict__ pp, float* __restrict__ pool) {
  int i = blockIdx.x * 256 + threadIdx.x;  // b*1024 + o
  int b = i >> 10, o = i & 1023;
  const float* base = pp + (size_t)b * 8192 + o;
  float m = base[0];
  #pragma unroll
  for (int tn = 1; tn < 8; tn++) m = fmaxf(m, base[tn * 1024]);
  pool[i] = m;
}

// ---------------------------------------------------------------- small FC layers fp32
__global__ void k_fc(const float* __restrict__ in, int Cc,
                     const float* __restrict__ W,
                     const float* __restrict__ bias,
                     const float* __restrict__ bng, const float* __restrict__ bnb,
                     int act, float* __restrict__ out, int O) {
  int i = blockIdx.x * 256 + threadIdx.x;
  if (i >= BB * O) return;
  int b = i / O, o = i % O;
  const float* xp = in + (size_t)b * Cc;
  const float* wp = W + (size_t)o * Cc;
  float s = 0.f;
  for (int c = 0; c < Cc; c += 4) {
    float4 xv = *(const float4*)(xp + c);
    float4 wv = *(const float4*)(wp + c);
    s += xv.x * wv.x + xv.y * wv.y + xv.z * wv.z + xv.w * wv.w;
  }
  if (bias) s += bias[o];
  const float BNS = 0.99999500003749966f;
  if (bng) s = s * (bng[o] * BNS) + bnb[o];
  if (act == 2) s = s > 0.f ? s : 0.2f * s;
  else if (act == 1) s = fmaxf(s, 0.f);
  out[i] = s;
}

// ---------------------------------------------------------------- host
extern "C" void kernel_launch(void* const* d_in, const int* in_sizes, int n_in,
                              void* d_out, int out_size, void* d_ws, size_t ws_size,
                              hipStream_t stream) {
  const float* x        = (const float*)d_in[0];
  const float* A        = (const float*)d_in[1];
  const float* P        = (const float*)d_in[2];
  const float* cl1_wr   = (const float*)d_in[3];
  const float* cl1_wi   = (const float*)d_in[4];
  const float* cl1_br   = (const float*)d_in[5];
  const float* cl1_bi   = (const float*)d_in[6];
  const float* cl2_wr   = (const float*)d_in[7];
  const float* cl2_wi   = (const float*)d_in[8];
  const float* cl2_br   = (const float*)d_in[9];
  const float* cl2_bi   = (const float*)d_in[10];
  const float* pt_c1_w  = (const float*)d_in[11];
  const float* pt_c2_w  = (const float*)d_in[12];
  const float* pt_bn1_g = (const float*)d_in[13];
  const float* pt_bn1_b = (const float*)d_in[14];
  const float* pt_bn2_g = (const float*)d_in[15];
  const float* pt_bn2_b = (const float*)d_in[16];
  const float* sa_qk_w  = (const float*)d_in[17];
  const float* sa_v_w   = (const float*)d_in[18];
  const float* sa_v_b   = (const float*)d_in[19];
  const float* sa_t_w   = (const float*)d_in[20];
  const float* sa_t_b   = (const float*)d_in[21];
  const float* sa_bn_g  = (const float*)d_in[22];
  const float* sa_bn_b  = (const float*)d_in[23];
  const float* fuse_w   = (const float*)d_in[24];
  const float* fuse_g   = (const float*)d_in[25];
  const float* fuse_b   = (const float*)d_in[26];
  const float* lin1_w   = (const float*)d_in[27];
  const float* bn6_g    = (const float*)d_in[28];
  const float* bn6_b    = (const float*)d_in[29];
  const float* lin2_w   = (const float*)d_in[30];
  const float* lin2_b   = (const float*)d_in[31];
  const float* bn7_g    = (const float*)d_in[32];
  const float* bn7_b    = (const float*)d_in[33];
  const float* lin3_w   = (const float*)d_in[34];
  const float* lin3_b   = (const float*)d_in[35];

  float* ws = (float*)d_ws;
  // ---- workspace layout (float offsets) ----
  const size_t oPts  = 0;                         // 49152
  const size_t oS    = 65536;                     // 16777216 f scratch (aliased per phase)
  const size_t oBigT = oS + 16777216;             // 10485760 (bf16 [16][1024][1280])
  const size_t oXf0  = oBigT + 10485760;          // 4194304
  const size_t oXf1  = oXf0 + 4194304;            // 4194304
  const size_t oH1T  = oXf1 + 4194304;            // 2097152 (h1T / diffT alias)
  const size_t oH2T  = oH1T + 2097152;            // 2097152
  const size_t oXkT  = oH2T + 2097152;            // 524288
  const size_t oXv   = oXkT + 524288;             // 2097152
  const size_t oAux  = oXv + 2097152;             // 8388608: phase1 eAT+J; phase2 part
  const size_t oGb   = oAux + 8388608;            // 4194304 (bf16 [16384][512])
  const size_t oW1c  = oGb + 4194304;             // 131072
  const size_t oW2c  = oW1c + 131072;             // 131072
  const size_t oCb1  = oW2c + 131072;             // 512
  const size_t oCb2  = oCb1 + 512;                // 512
  const size_t oPool = oCb2 + 512;                // 16384
  const size_t oFc1  = oPool + 16384;             // 8192
  const size_t oFc2  = oFc1 + 8192;               // 4096
  const size_t oWp   = oFc2 + 4096;               // bf16 weight pool

  float*  pts  = ws + oPts;
  // scratch S aliases: phase1 eA|Mj -> G1b|G2b -> Eb (bf16, 32MB); poolP in upper half
  float2* eA   = (float2*)(ws + oS);
  float2* Mj   = (float2*)(ws + oS + 8388608);
  u16*    G1b  = (u16*)(ws + oS);
  u16*    G2b  = (u16*)(ws + oS + 8388608);
  u16*    Eb   = (u16*)(ws + oS);                 // bf16 [16][1024][1024] = 8388608 f
  float*  poolP= ws + oS + 8388608;               // [16][8][1024]
  u16*    bigT = (u16*)(ws + oBigT);
  float*  Xf0  = ws + oXf0;
  float*  Xf1  = ws + oXf1;
  u16*    h1T  = (u16*)(ws + oH1T);
  u16*    diffT= (u16*)(ws + oH1T);
  u16*    h2T  = (u16*)(ws + oH2T);
  u16*    xkT  = (u16*)(ws + oXkT);
  u16*    xv   = (u16*)(ws + oXv);
  u16*    eAT  = (u16*)(ws + oAux);               // phase1
  u16*    Jb   = (u16*)(ws + oAux + 4194304);     // phase1
  float*  partP= ws + oAux;                       // phase2 (eAT dead): [16][1024][8][2]
  u16*    Gb   = (u16*)(ws + oGb);
  u16*    W1c  = (u16*)(ws + oW1c);
  u16*    W2c  = (u16*)(ws + oW2c);
  float*  cb1  = ws + oCb1;
  float*  cb2  = ws + oCb2;
  float*  pool = ws + oPool;
  float*  fc1  = ws + oFc1;
  float*  fc2  = ws + oFc2;
  u16*    wp   = (u16*)(ws + oWp);
  u16* wp_pt1  = wp;                // 65536
  u16* wp_pt2  = wp + 65536;        // 65536
  u16* wp_qkv  = wp + 131072;       // 4 x 320*256 = 327680
  u16* wp_t    = wp + 458752;       // 4*65536
  u16* wp_fuse = wp + 720896;       // 1310720

  // ---- merged prep (pts + all weight casts, 1 launch) ----
  k_prep<<<10052, 256, 0, stream>>>(x, pts,
      pt_c1_w, pt_c2_w, sa_qk_w, sa_v_w, sa_t_w, fuse_w,
      cl1_wr, cl1_wi, cl2_wr, cl2_wi, cl1_br, cl1_bi, cl2_br, cl2_bi,
      wp_pt1, wp_pt2, wp_qkv, wp_t, wp_fuse, W1c, W2c, cb1, cb2);

  // ---- VecKM: M = J @ eA via MFMA ----
  k_phase<<<16384, 256, 0, stream>>>(pts, A, eA);
  k_eat<<<2048, 256, 0, stream>>>(eA, eAT);
  k_jbuild<<<16384, 256, 0, stream>>>(pts, Jb);
  k_mm<128,0,0><<<512, 256, 0, stream>>>(Jb, 1048576, 1024, eAT, 524288, 1024, 1024, 8, 4,
      nullptr, nullptr, nullptr, nullptr, 0, nullptr, 0, 0,
      (float*)Mj, 524288, 512, nullptr, 0, 0, 0, nullptr, 0, 0, nullptr, nullptr);
  k_norm<<<BB * NN, 256, 0, stream>>>(Mj, eA, pts, P, Gb);

  // ---- complex linears as single real MFMA GEMMs (K=512) ----
  k_mm<128,0,0><<<512, 256, 0, stream>>>(Gb, 0, 512, W1c, 0, 512, 512, 128, 4,
      nullptr, nullptr, nullptr, cb1, 1, nullptr, 0, 0,
      nullptr, 0, 0, G1b, 0, 512, 1, nullptr, 0, 0, nullptr, nullptr);
  k_mm<128,0,0><<<512, 256, 0, stream>>>(G1b, 0, 512, W2c, 0, 512, 512, 128, 4,
      nullptr, nullptr, nullptr, cb2, 0, nullptr, 0, 0,
      nullptr, 0, 0, G2b, 0, 512, 1, nullptr, 0, 0, nullptr, nullptr);
  k_g2<<<16384, 256, 0, stream>>>(G2b, bigT);

  const long bsBigT = 1310720;   // ushort units
  const long bsH256 = 262144;
  const long bsXkT  = 65536;
  const long bsXvU  = 262144;
  const long bsF    = 262144;
  const long bsEU   = 1048576;   // Eb bf16 [1024][1024]

  // ---- pt convs (BM=128, r7 config) ----
  k_mm<128,0,0><<<256, 256, 0, stream>>>(wp_pt1, 0, 256, bigT + 1024, bsBigT, 1280, 256, 2, 8,
      nullptr, pt_bn1_g, pt_bn1_b, nullptr, 1, nullptr, 0, 0,
      nullptr, 0, 0, nullptr, 0, 0, 0, h1T, bsH256, 256, nullptr, nullptr);
  k_mm<128,0,0><<<256, 256, 0, stream>>>(wp_pt2, 0, 256, h1T, bsH256, 256, 256, 2, 8,
      nullptr, pt_bn2_g, pt_bn2_b, nullptr, 1, nullptr, 0, 0,
      Xf0, bsF, 1024, nullptr, 0, 0, 0, h2T, bsH256, 256, nullptr, nullptr);

  // ---- 4 SA layers (fused qkv conv; materialized bf16 E; stats fused into energy GEMM) ----
  for (int i = 0; i < 4; i++) {
    const u16* XinT   = (i == 0) ? h2T : (bigT + (i - 1) * 256);
    long       xinT_bs= (i == 0) ? bsH256 : bsBigT;
    int        xinT_ld= (i == 0) ? 256 : 1280;
    float*     XinF   = (i & 1) ? Xf1 : Xf0;
    float*     XoutF  = (i & 1) ? Xf0 : Xf1;
    const u16* qkvw = wp_qkv + (size_t)i * 81920;
    const u16* tw   = wp_t + (size_t)i * 65536;

    // fused qkv conv: stacked [320][256] weights; tile0 -> xkT [n][64], tiles1-4 -> xv [c][n]+bias
    k_mm<64,0,1><<<BB * 5 * 8, 256, 0, stream>>>(qkvw, 0, 256, XinT, xinT_bs, xinT_ld, 256, 5, 8,
        sa_v_b + i * 256, nullptr, nullptr, nullptr, 0, nullptr, 0, 0,
        nullptr, 0, 0, xv, bsXvU, 1024, 0, xkT, bsXkT, 64, nullptr, nullptr);
    // energy E = xkT * xkT^T -> bf16 [n][m] + fused per-tile softmax stats
    k_mm<128,1,0><<<1024, 256, 0, stream>>>(xkT, bsXkT, 64, xkT, bsXkT, 64, 64, 8, 8,
        nullptr, nullptr, nullptr, nullptr, 0, nullptr, 0, 0,
        nullptr, 0, 0, Eb, bsEU, 1024, 0, nullptr, 0, 0, nullptr, partP);
    k_xratt<<<256, 256, 0, stream>>>(xv, Eb, partP, XinF, bsF, diffT);
    // t conv: relu(bn(tw@diff + tb)) + Xin -> XoutF fp32 + bigT slice bf16
    k_mm<128,0,0><<<256, 256, 0, stream>>>(tw, 0, 256, diffT, bsH256, 256, 256, 2, 8,
        sa_t_b + i * 256, sa_bn_g + i * 256, sa_bn_b + i * 256, nullptr, 1,
        XinF, bsF, 0,
        XoutF, bsF, 1024, nullptr, 0, 0, 0, bigT + i * 256, bsBigT, 1280, nullptr, nullptr);
  }

  // ---- fuse conv with fused max pool (coalesced partials) ----
  k_mm<128,0,0><<<1024, 256, 0, stream>>>(wp_fuse, 0, 1280, bigT, bsBigT, 1280, 1280, 8, 8,
      nullptr, fuse_g, fuse_b, nullptr, 2, nullptr, 0, 0,
      nullptr, 0, 0, nullptr, 0, 0, 0, nullptr, 0, 0, poolP, nullptr);
  k_pool8<<<64, 256, 0, stream>>>(poolP, pool);

  // ---- MLP head ----
  k_fc<<<32, 256, 0, stream>>>(pool, 1024, lin1_w, nullptr, bn6_g, bn6_b, 2, fc1, 512);
  k_fc<<<16, 256, 0, stream>>>(fc1, 512, lin2_w, lin2_b, bn7_g, bn7_b, 2, fc2, 256);
  k_fc<<<3, 256, 0, stream>>>(fc2, 256, lin3_w, lin3_b, nullptr, nullptr, 0, (float*)d_out, 40);
}

// Round 10
// 988.474 us; speedup vs baseline: 1.1268x; 1.0270x over previous
//
#include <hip/hip_runtime.h>
#include <math.h>

#define BB 16
#define NN 1024
#define DD 256

typedef unsigned short u16;
typedef unsigned int uint32;
typedef __attribute__((ext_vector_type(8))) short s8v;   // 8 bf16 (4 VGPRs)
typedef __attribute__((ext_vector_type(4))) float f4v;   // 4 fp32 acc

__device__ __forceinline__ u16 f2b(float f) {            // RNE fp32->bf16
  uint32 u = __float_as_uint(f);
  return (u16)((u + 0x7fffu + ((u >> 16) & 1u)) >> 16);
}
__device__ __forceinline__ float b2f(u16 u) {
  return __uint_as_float(((uint32)u) << 16);
}
__device__ __forceinline__ float blo(uint32 w) { return __uint_as_float(w << 16); }
__device__ __forceinline__ float bhi(uint32 w) { return __uint_as_float(w & 0xffff0000u); }

// async global->LDS DMA, 16B per lane; lds base must be wave-uniform (HW scatters +lane*16B)
__device__ __forceinline__ void gld16(u16* lds, const u16* g) {
  __builtin_amdgcn_global_load_lds(
      (const __attribute__((address_space(1))) unsigned int*)g,
      (__attribute__((address_space(3))) unsigned int*)lds, 16, 0, 0);
}

__device__ __forceinline__ float waveRedSum(float v) {
  #pragma unroll
  for (int o = 32; o; o >>= 1) v += __shfl_xor(v, o, 64);
  return v;
}

// ---------------------------------------------------------------- merged prep: pts + all weight casts
__global__ void k_prep(const float* __restrict__ x, float* __restrict__ pts,
                       const float* __restrict__ pt1w, const float* __restrict__ pt2w,
                       const float* __restrict__ qkw, const float* __restrict__ vw,
                       const float* __restrict__ tw, const float* __restrict__ fw,
                       const float* __restrict__ w1r, const float* __restrict__ w1i,
                       const float* __restrict__ w2r, const float* __restrict__ w2i,
                       const float* __restrict__ b1r, const float* __restrict__ b1i,
                       const float* __restrict__ b2r, const float* __restrict__ b2i,
                       u16* __restrict__ wp_pt1, u16* __restrict__ wp_pt2,
                       u16* __restrict__ wp_qkv, u16* __restrict__ wp_t,
                       u16* __restrict__ wp_fuse,
                       u16* __restrict__ W1c, u16* __restrict__ W2c,
                       float* __restrict__ cb1, float* __restrict__ cb2) {
  int i = blockIdx.x * 256 + threadIdx.x;
  if (i < 16384) {
    int b = i >> 10, n = i & 1023;
    const float* xb = x + (size_t)b * 3072;
    pts[i * 3 + 0] = xb[n];
    pts[i * 3 + 1] = xb[1024 + n];
    pts[i * 3 + 2] = xb[2048 + n];
  } else if (i < 81920) {
    int k = i - 16384;  wp_pt1[k] = f2b(pt1w[k]);
  } else if (i < 147456) {
    int k = i - 81920;  wp_pt2[k] = f2b(pt2w[k]);
  } else if (i < 475136) {
    int k = i - 147456;
    int layer = k / 81920, rem = k % 81920;
    int r = rem >> 8, c = rem & 255;
    float v = (r < 64) ? qkw[layer * 16384 + r * 256 + c]
                       : vw[layer * 65536 + (r - 64) * 256 + c];
    wp_qkv[k] = f2b(v);
  } else if (i < 737280) {
    int k = i - 475136; wp_t[k] = f2b(tw[k]);
  } else if (i < 2048000) {
    int k = i - 737280; wp_fuse[k] = f2b(fw[k]);
  } else if (i < 2310144) {
    int k = i - 2048000;
    int op = k >> 9, c2 = k & 511, c = c2 >> 1, pl = c2 & 1;
    float v;
    if (op < 256) v = pl ? -w1i[op * 256 + c] : w1r[op * 256 + c];
    else          v = pl ?  w1r[(op - 256) * 256 + c] : w1i[(op - 256) * 256 + c];
    W1c[k] = f2b(v);
  } else if (i < 2572288) {
    int k = i - 2310144;
    int op = k >> 9, c2 = k & 511, c = c2 >> 1, pl = c2 & 1;
    float v;
    if (op < 256) v = pl ? -w2i[op * 256 + c] : w2r[op * 256 + c];
    else          v = pl ?  w2r[(op - 256) * 256 + c] : w2i[(op - 256) * 256 + c];
    W2c[k] = f2b(v);
  } else if (i < 2572800) {
    int k = i - 2572288; cb1[k] = (k < 256) ? b1r[k] : b1i[k - 256];
  } else if (i < 2573312) {
    int k = i - 2572800; cb2[k] = (k < 256) ? b2r[k] : b2i[k - 256];
  }
}

// ---------------------------------------------------------------- fused phase+eAT (tiles) + jbuild (region)
// bid < 2048: compute eA tile [64n][32d] (sincos in-block), write eA fp32 + eAT bf16 transposed
// bid >= 2048: jbuild row (bid-2048 = b*1024+n), J bf16 [b][n][1024]
__global__ void k_pe(const float* __restrict__ pts, const float* __restrict__ A,
                     float2* __restrict__ eA, u16* __restrict__ eAT,
                     u16* __restrict__ J) {
  __shared__ u16 cosT[32][72], sinT[32][72];
  int bid = blockIdx.x;
  int t = threadIdx.x;
  if (bid < 2048) {
    int dt = bid & 7, nt = (bid >> 3) & 15, b = bid >> 7;
    int d0 = dt * 32, n0 = nt * 64;
    int n = t >> 2, dg = (t & 3) * 8;
    const float* pp = pts + ((size_t)(b * 1024 + n0 + n)) * 3;
    float p0 = pp[0], p1 = pp[1], p2 = pp[2];
    float2 ev[8];
    #pragma unroll
    for (int j = 0; j < 8; j++) {
      int d = d0 + dg + j;
      float ta = p0 * A[d] + p1 * A[256 + d] + p2 * A[512 + d];
      float s, c; sincosf(ta, &s, &c);
      ev[j] = make_float2(c, s);
      cosT[dg + j][n] = f2b(c);
      sinT[dg + j][n] = f2b(s);
    }
    float2* dst = eA + ((size_t)(b * 1024 + n0 + n)) * 256 + d0 + dg;
    #pragma unroll
    for (int j = 0; j < 8; j++) dst[j] = ev[j];
    __syncthreads();
    {
      int rr = t >> 2, ng = (t & 3) * 16;
      int d = rr >> 1, cmp = rr & 1;
      const u16* src = (cmp ? &sinT[d][ng] : &cosT[d][ng]);
      uint4 v0 = *(const uint4*)src;
      uint4 v1 = *(const uint4*)(src + 8);
      u16* dstT = eAT + ((size_t)(b * 512 + 2 * d0 + rr)) * 1024 + n0 + ng;
      *(uint4*)dstT = v0;
      *(uint4*)(dstT + 8) = v1;
    }
  } else {
    int bid2 = bid - 2048;
    int b = bid2 >> 10, n = bid2 & 1023;
    const float* pb = pts + (size_t)b * 3072;
    float pnx = pb[n * 3], pny = pb[n * 3 + 1], pnz = pb[n * 3 + 2];
    int m = t * 4;
    const float* pm = pb + (size_t)m * 3;
    float4 a = *(const float4*)pm;
    float4 bq = *(const float4*)(pm + 4);
    float4 c = *(const float4*)(pm + 8);
    float dx, dy, dz, d2;
    dx = a.x - pnx;  dy = a.y - pny;  dz = a.z - pnz;  d2 = dx*dx + dy*dy + dz*dz;
    float j0 = __expf(-18.0f * d2);
    dx = a.w - pnx;  dy = bq.x - pny; dz = bq.y - pnz; d2 = dx*dx + dy*dy + dz*dz;
    float j1 = __expf(-18.0f * d2);
    dx = bq.z - pnx; dy = bq.w - pny; dz = c.x - pnz;  d2 = dx*dx + dy*dy + dz*dz;
    float j2 = __expf(-18.0f * d2);
    dx = c.y - pnx;  dy = c.z - pny;  dz = c.w - pnz;  d2 = dx*dx + dy*dy + dz*dz;
    float j3 = __expf(-18.0f * d2);
    uint32 lo = (uint32)f2b(j0) | ((uint32)f2b(j1) << 16);
    uint32 hi = (uint32)f2b(j2) | ((uint32)f2b(j3) << 16);
    *(uint2*)(J + (size_t)bid2 * 1024 + m) = make_uint2(lo, hi);
  }
}

// ------------------------------------------ G = norm(M*conj(eA))*16 + exp(i pts@P) -> interleaved bf16 [bn][512]
__global__ void k_norm(const float2* __restrict__ M, const float2* __restrict__ eA,
                       const float* __restrict__ pts, const float* __restrict__ P,
                       u16* __restrict__ Gb) {
  int bn = blockIdx.x; int c = threadIdx.x;
  size_t idx = (size_t)bn * DD + c;
  float2 m = M[idx], e = eA[idx];
  float gr = m.x * e.x + m.y * e.y;
  float gi = m.y * e.x - m.x * e.y;
  float s = gr * gr + gi * gi;
  s = waveRedSum(s);
  __shared__ float red[4];
  if ((c & 63) == 0) red[c >> 6] = s;
  __syncthreads();
  float tot = red[0] + red[1] + red[2] + red[3];
  float scale = 16.0f / sqrtf(tot);
  float p0 = pts[bn * 3], p1 = pts[bn * 3 + 1], p2 = pts[bn * 3 + 2];
  float tp = p0 * P[c] + p1 * P[256 + c] + p2 * P[512 + c];
  float sp, cp; sincosf(tp, &sp, &cp);
  uint32 pk = (uint32)f2b(gr * scale + cp) | ((uint32)f2b(gi * scale + sp) << 16);
  *(uint32*)(Gb + idx * 2) = pk;
}

// ---------------------------------------------------------------- Gr=|G|^2 -> bigT[:,1024+c] bf16
__global__ void k_g2(const u16* __restrict__ G2b, u16* __restrict__ bigT) {
  int i = blockIdx.x * 256 + threadIdx.x;   // 16384*256
  int row = i >> 8, c = i & 255;
  float re = b2f(G2b[(size_t)row * 512 + 2 * c]);
  float im = b2f(G2b[(size_t)row * 512 + 2 * c + 1]);
  bigT[(size_t)row * 1280 + 1024 + c] = f2b(re * re + im * im);
}

// ---------------------------------------------------------------- generic bf16 MFMA GEMM
// D[M][N] = A[M][K] * Bt[N][K]^T  (both bf16, k-contiguous), fp32 accum.
// Staging via global_load_lds width=16 (LDS layout = wave base + lane*16B).
// STATS: per-M-row softmax partials over this block's 128-col tile.
// QKV: tile tm==0 -> outT (xkT); tiles tm>0 -> outB (xv) with bias[mo-64].
template<int BM, int STATS, int QKV>
__launch_bounds__(256)
__global__ void k_mm(const u16* __restrict__ Ab, long a_bs, int lda,
                     const u16* __restrict__ Btb, long b_bs, int ldb,
                     int K, int tiles_m, int tiles_n,
                     const float* __restrict__ bias,
                     const float* __restrict__ bng, const float* __restrict__ bnb,
                     const float* __restrict__ cbias,
                     int act,
                     const float* __restrict__ res, long res_bs, int res_sub,
                     float* __restrict__ outF, long outF_bs, int ldF,
                     u16* __restrict__ outB, long outB_bs, int ldBo, int ileave,
                     u16* __restrict__ outT, long outT_bs, int ldT,
                     float* __restrict__ outPool,
                     float* __restrict__ outStats) {
  constexpr int BN = 128;
  constexpr int WM = (BM == 128) ? 64 : 32;
  constexpr int MI = WM / 16;
  __shared__ u16 smem[BN * BM];            // >= As(BM*32)+Bs(BN*32); also T[BN][BM] / reductions
  u16* As = smem;
  u16* Bs = smem + BM * 32;
  int t = threadIdx.x;
  int l = t & 63, w = t >> 6;
  int p = l & 15, q = l >> 4;
  int bid = blockIdx.x;
  int tn = bid % tiles_n;
  int tm = (bid / tiles_n) % tiles_m;
  int b  = bid / (tiles_n * tiles_m);
  int m0 = tm * BM, n0 = tn * BN;
  int wm = w >> 1, wn = w & 1;
  const u16* Ap = Ab + (size_t)b * a_bs;
  const u16* Bp = Btb + (size_t)b * b_bs;

  f4v acc[MI][4];
  #pragma unroll
  for (int i = 0; i < MI; i++)
    #pragma unroll
    for (int j = 0; j < 4; j++) acc[i][j] = (f4v){0.f, 0.f, 0.f, 0.f};

  int arow = t >> 2, kg = (t & 3) * 8;
  for (int k0 = 0; k0 < K; k0 += 32) {
    __syncthreads();
    #pragma unroll
    for (int it = 0; it < BM / 64; it++)
      gld16(As + it * 2048 + w * 512,
            Ap + (size_t)(m0 + it * 64 + arow) * lda + k0 + kg);
    #pragma unroll
    for (int it = 0; it < 2; it++)
      gld16(Bs + it * 2048 + w * 512,
            Bp + (size_t)(n0 + it * 64 + arow) * ldb + k0 + kg);
    __syncthreads();
    s8v af[MI], bf[4];
    #pragma unroll
    for (int i = 0; i < MI; i++)
      af[i] = *(const s8v*)&As[(wm * WM + i * 16 + p) * 32 + q * 8];
    #pragma unroll
    for (int j = 0; j < 4; j++)
      bf[j] = *(const s8v*)&Bs[(wn * 64 + j * 16 + p) * 32 + q * 8];
    #pragma unroll
    for (int i = 0; i < MI; i++)
      #pragma unroll
      for (int j = 0; j < 4; j++)
        acc[i][j] = __builtin_amdgcn_mfma_f32_16x16x32_bf16(af[i], bf[j], acc[i][j], 0, 0, 0);
  }

  __syncthreads();   // LDS reuse (transpose / reductions)

  u16* oB = outB;
  u16* oT = outT;
  if (QKV) { if (tm == 0) oB = nullptr; else oT = nullptr; }

  float cbv[4];
  #pragma unroll
  for (int j = 0; j < 4; j++) {
    int no = n0 + wn * 64 + j * 16 + p;
    cbv[j] = cbias ? cbias[no] : 0.0f;
  }
  float pmax[MI][4];
  #pragma unroll
  for (int i = 0; i < MI; i++)
    #pragma unroll
    for (int r = 0; r < 4; r++) pmax[i][r] = -3.0e38f;
  const float BNS = 0.99999500003749966f;  // 1/sqrt(1+1e-5)
  #pragma unroll
  for (int i = 0; i < MI; i++) {
    #pragma unroll
    for (int r = 0; r < 4; r++) {
      int mo = m0 + wm * WM + i * 16 + q * 4 + r;
      float mult = 1.f, add = 0.f;
      if (QKV) {
        if (tm > 0 && bias) add = bias[mo - 64];
      } else {
        if (bias) add = bias[mo];
        if (bng) { float s = bng[mo] * BNS; add = add * s + bnb[mo]; mult = s; }
      }
      #pragma unroll
      for (int j = 0; j < 4; j++) {
        int no = n0 + wn * 64 + j * 16 + p;
        float v = acc[i][j][r];
        v = v * mult + add;
        if (cbias) v += cbv[j];
        if (act == 1) v = fmaxf(v, 0.f);
        else if (act == 2) v = v > 0.f ? v : 0.2f * v;
        if (res) {
          float rv = res[(size_t)b * res_bs + (size_t)mo * NN + no];
          v = res_sub ? rv - v : rv + v;
        }
        if (outPool) pmax[i][r] = fmaxf(pmax[i][r], v);
        if (outF) outF[(size_t)b * outF_bs + (size_t)mo * ldF + no] = v;
        if (oB) {
          int moB = QKV ? (mo - 64) : mo;
          int noo = ileave ? (((no & 255) << 1) | (no >> 8)) : no;
          oB[(size_t)b * outB_bs + (size_t)moB * ldBo + noo] = f2b(v);
        }
        if (oT) smem[(wn * 64 + j * 16 + p) * BM + (mo - m0)] = f2b(v);
      }
    }
  }
  if (oT) {
    __syncthreads();
    constexpr int CPR = BM / 8;            // threads per row (8 bf16 each)
    constexpr int RPP = 256 / CPR;
    int row0 = t / CPR, cg = (t % CPR) * 8;
    for (int rr = row0; rr < BN; rr += RPP) {
      float4 v = *(const float4*)&smem[rr * BM + cg];
      *(float4*)(oT + (size_t)b * outT_bs + (size_t)(n0 + rr) * ldT + m0 + cg) = v;
    }
  }
  if (outPool) {
    float* pf = (float*)smem;              // [BM][2]
    #pragma unroll
    for (int i = 0; i < MI; i++)
      #pragma unroll
      for (int r = 0; r < 4; r++) {
        float m = pmax[i][r];
        #pragma unroll
        for (int o = 1; o < 16; o <<= 1) m = fmaxf(m, __shfl_xor(m, o, 64));
        if (p == 0) pf[(wm * WM + i * 16 + q * 4 + r) * 2 + wn] = m;
      }
    __syncthreads();
    if (t < BM) {
      float mv = fmaxf(pf[t * 2], pf[t * 2 + 1]);
      outPool[((size_t)b * tiles_n + tn) * (size_t)(tiles_m * BM) + m0 + t] = mv;
    }
  }
  if (STATS) {
    float* sm1 = (float*)smem;             // [BM][2] max
    float* sm2 = sm1 + BM * 2;             // [BM][2] expsum
    #pragma unroll
    for (int i = 0; i < MI; i++)
      #pragma unroll
      for (int r = 0; r < 4; r++) {
        float m = fmaxf(fmaxf(acc[i][0][r], acc[i][1][r]), fmaxf(acc[i][2][r], acc[i][3][r]));
        #pragma unroll
        for (int o = 1; o < 16; o <<= 1) m = fmaxf(m, __shfl_xor(m, o, 64));
        if (p == 0) sm1[(wm * WM + i * 16 + q * 4 + r) * 2 + wn] = m;
      }
    __syncthreads();
    #pragma unroll
    for (int i = 0; i < MI; i++)
      #pragma unroll
      for (int r = 0; r < 4; r++) {
        int row = wm * WM + i * 16 + q * 4 + r;
        float g = fmaxf(sm1[row * 2], sm1[row * 2 + 1]);
        float s = __expf(acc[i][0][r] - g) + __expf(acc[i][1][r] - g) +
                  __expf(acc[i][2][r] - g) + __expf(acc[i][3][r] - g);
        #pragma unroll
        for (int o = 1; o < 16; o <<= 1) s += __shfl_xor(s, o, 64);
        if (p == 0) sm2[row * 2 + wn] = s;
      }
    __syncthreads();
    if (t < BM) {
      float g = fmaxf(sm1[t * 2], sm1[t * 2 + 1]);
      float ssum = sm2[t * 2] + sm2[t * 2 + 1];
      *(float2*)(outStats + (((size_t)b * (tiles_m * BM) + m0 + t) * tiles_n + tn) * 2)
          = make_float2(g, ssum);
    }
  }
}

// ---------------------------------------------------------------- fused softmax+colsum+xr+diff (E bf16, symmetric)
// m-tile 64 (grid 512 = 2 blocks/CU). D[c][m] = sum_n xv[c][n]*p[n][m],
// p[n][m] = exp(E[m][n]-rmax[n])*rinv[n]; rmax/rinv combined from per-tile partials.
// diffT[m][c] = Xin[c][m] - D[c][m] / (1e-9 + colsum[m])
__launch_bounds__(256)
__global__ void k_xratt(const u16* __restrict__ xv_, const u16* __restrict__ E,
                        const float* __restrict__ part_,
                        const float* __restrict__ XinF, long xinF_bs,
                        u16* __restrict__ diffT) {
  __shared__ u16 smem[16384];          // As(0..4095) Bs(4096..6143); reuse: T[64][128]
  __shared__ float colred[64][4];
  __shared__ float rmS[1024];
  __shared__ float riS[1024];
  u16* As = smem;
  u16* Bs = smem + 4096;
  int t = threadIdx.x;
  int l = t & 63, w = t >> 6;
  int p = l & 15, q = l >> 4;
  int bid = blockIdx.x;
  int mt = bid & 15, ct = (bid >> 4) & 1, b = bid >> 5;
  int c0 = ct * 128, m0 = mt * 64;
  int wm = w;                          // wave covers c-slice wm*32
  const u16* Ap = xv_ + (size_t)b * 262144;
  const u16* Ep = E + ((size_t)b << 20);
  // prologue: combine 8 tile-partials per row -> rmax, 1/expsum
  {
    const float2* pbase = (const float2*)(part_ + (size_t)b * 16384);
    for (int row = t; row < 1024; row += 256) {
      const float2* pp = pbase + row * 8;
      float2 vv[8];
      #pragma unroll
      for (int k = 0; k < 8; k++) vv[k] = pp[k];
      float g = vv[0].x;
      #pragma unroll
      for (int k = 1; k < 8; k++) g = fmaxf(g, vv[k].x);
      float s = 0.f;
      #pragma unroll
      for (int k = 0; k < 8; k++) s += vv[k].y * __expf(vv[k].x - g);
      rmS[row] = g;
      riS[row] = 1.0f / s;
    }
  }
  f4v acc[2][4];
  #pragma unroll
  for (int i = 0; i < 2; i++)
    #pragma unroll
    for (int j = 0; j < 4; j++) acc[i][j] = (f4v){0.f, 0.f, 0.f, 0.f};
  float colpart = 0.f;
  int arow = t >> 2, kg = (t & 3) * 8;
  for (int k0 = 0; k0 < 1024; k0 += 32) {
    __syncthreads();
    #pragma unroll
    for (int it = 0; it < 2; it++)
      gld16(As + it * 2048 + w * 512,
            Ap + (size_t)(c0 + it * 64 + arow) * 1024 + k0 + kg);
    float4 ma0 = *(const float4*)&rmS[k0 + kg];
    float4 ma1 = *(const float4*)&rmS[k0 + kg + 4];
    float4 ia0 = *(const float4*)&riS[k0 + kg];
    float4 ia1 = *(const float4*)&riS[k0 + kg + 4];
    {
      int r = arow;                    // m row 0..63
      uint4 e8 = *(const uint4*)(Ep + (size_t)(m0 + r) * 1024 + k0 + kg);
      float p0 = __expf(blo(e8.x) - ma0.x) * ia0.x;
      float p1 = __expf(bhi(e8.x) - ma0.y) * ia0.y;
      float p2 = __expf(blo(e8.y) - ma0.z) * ia0.z;
      float p3 = __expf(bhi(e8.y) - ma0.w) * ia0.w;
      float p4 = __expf(blo(e8.z) - ma1.x) * ia1.x;
      float p5 = __expf(bhi(e8.z) - ma1.y) * ia1.y;
      float p6 = __expf(blo(e8.w) - ma1.z) * ia1.z;
      float p7 = __expf(bhi(e8.w) - ma1.w) * ia1.w;
      float s8 = ((p0 + p1) + (p2 + p3)) + ((p4 + p5) + (p6 + p7));
      colpart += s8;
      uint32 w0 = (uint32)f2b(p0) | ((uint32)f2b(p1) << 16);
      uint32 w1 = (uint32)f2b(p2) | ((uint32)f2b(p3) << 16);
      uint32 w2 = (uint32)f2b(p4) | ((uint32)f2b(p5) << 16);
      uint32 w3 = (uint32)f2b(p6) | ((uint32)f2b(p7) << 16);
      *(uint4*)&Bs[r * 32 + kg] = make_uint4(w0, w1, w2, w3);
    }
    __syncthreads();
    s8v af[2], bf[4];
    #pragma unroll
    for (int i = 0; i < 2; i++)
      af[i] = *(const s8v*)&As[(wm * 32 + i * 16 + p) * 32 + q * 8];
    #pragma unroll
    for (int j = 0; j < 4; j++)
      bf[j] = *(const s8v*)&Bs[(j * 16 + p) * 32 + q * 8];
    #pragma unroll
    for (int i = 0; i < 2; i++)
      #pragma unroll
      for (int j = 0; j < 4; j++)
        acc[i][j] = __builtin_amdgcn_mfma_f32_16x16x32_bf16(af[i], bf[j], acc[i][j], 0, 0, 0);
  }
  colred[arow][t & 3] = colpart;
  __syncthreads();
  float csv[4];
  #pragma unroll
  for (int j = 0; j < 4; j++) {
    int ml = j * 16 + p;
    csv[j] = 1.0f / (1e-9f + colred[ml][0] + colred[ml][1] + colred[ml][2] + colred[ml][3]);
  }
  u16* T = smem;                       // [64 m][128 c]
  #pragma unroll
  for (int i = 0; i < 2; i++) {
    #pragma unroll
    for (int r = 0; r < 4; r++) {
      int cl = wm * 32 + i * 16 + q * 4 + r;
      int c = c0 + cl;
      #pragma unroll
      for (int j = 0; j < 4; j++) {
        int ml = j * 16 + p;
        float v = acc[i][j][r] * csv[j];
        float rv = XinF[(size_t)b * xinF_bs + (size_t)c * 1024 + m0 + ml];
        T[ml * 128 + cl] = f2b(rv - v);
      }
    }
  }
  __syncthreads();
  int rr0 = t >> 4, cg = (t & 15) * 8;
  #pragma unroll
  for (int k = 0; k < 4; k++) {
    int rr = rr0 + k * 16;
    *(float4*)(diffT + (size_t)b * 262144 + (size_t)(m0 + rr) * 256 + c0 + cg) =
        *(const float4*)&T[rr * 128 + cg];
  }
}

// ---------------------------------------------------------------- fused head: pool reduce + fc1 + fc2 + fc3
__global__ void k_head(const float* __restrict__ poolP,
                       const float* __restrict__ lin1_w,
                       const float* __restrict__ bn6_g, const float* __restrict__ bn6_b,
                       const float* __restrict__ lin2_w, const float* __restrict__ lin2_b,
                       const float* __restrict__ bn7_g, const float* __restrict__ bn7_b,
                       const float* __restrict__ lin3_w, const float* __restrict__ lin3_b,
                       float* __restrict__ out) {
  int b = blockIdx.x, t = threadIdx.x;
  __shared__ float pl[1024];
  __shared__ float h1[512];
  __shared__ float h2[256];
  const float BNS = 0.99999500003749966f;
  for (int o = t; o < 1024; o += 256) {
    const float* base = poolP + (size_t)b * 8192 + o;
    float m = base[0];
    #pragma unroll
    for (int tn = 1; tn < 8; tn++) m = fmaxf(m, base[tn * 1024]);
    pl[o] = m;
  }
  __syncthreads();
  for (int o = t; o < 512; o += 256) {
    const float* wp = lin1_w + (size_t)o * 1024;
    float s = 0.f;
    for (int c = 0; c < 1024; c += 4) {
      float4 xv = *(const float4*)(pl + c);
      float4 wv = *(const float4*)(wp + c);
      s += xv.x * wv.x + xv.y * wv.y + xv.z * wv.z + xv.w * wv.w;
    }
    s = s * (bn6_g[o] * BNS) + bn6_b[o];
    h1[o] = s > 0.f ? s : 0.2f * s;
  }
  __syncthreads();
  {
    int o = t;
    const float* wp = lin2_w + (size_t)o * 512;
    float s = 0.f;
    for (int c = 0; c < 512; c += 4) {
      float4 xv = *(const float4*)(h1 + c);
      float4 wv = *(const float4*)(wp + c);
      s += xv.x * wv.x + xv.y * wv.y + xv.z * wv.z + xv.w * wv.w;
    }
    s += lin2_b[o];
    s = s * (bn7_g[o] * BNS) + bn7_b[o];
    h2[o] = s > 0.f ? s : 0.2f * s;
  }
  __syncthreads();
  if (t < 40) {
    const float* wp = lin3_w + (size_t)t * 256;
    float s = 0.f;
    for (int c = 0; c < 256; c += 4) {
      float4 xv = *(const float4*)(h2 + c);
      float4 wv = *(const float4*)(wp + c);
      s += xv.x * wv.x + xv.y * wv.y + xv.z * wv.z + xv.w * wv.w;
    }
    out[b * 40 + t] = s + lin3_b[t];
  }
}

// ---------------------------------------------------------------- host
extern "C" void kernel_launch(void* const* d_in, const int* in_sizes, int n_in,
                              void* d_out, int out_size, void* d_ws, size_t ws_size,
                              hipStream_t stream) {
  const float* x        = (const float*)d_in[0];
  const float* A        = (const float*)d_in[1];
  const float* P        = (const float*)d_in[2];
  const float* cl1_wr   = (const float*)d_in[3];
  const float* cl1_wi   = (const float*)d_in[4];
  const float* cl1_br   = (const float*)d_in[5];
  const float* cl1_bi   = (const float*)d_in[6];
  const float* cl2_wr   = (const float*)d_in[7];
  const float* cl2_wi   = (const float*)d_in[8];
  const float* cl2_br   = (const float*)d_in[9];
  const float* cl2_bi   = (const float*)d_in[10];
  const float* pt_c1_w  = (const float*)d_in[11];
  const float* pt_c2_w  = (const float*)d_in[12];
  const float* pt_bn1_g = (const float*)d_in[13];
  const float* pt_bn1_b = (const float*)d_in[14];
  const float* pt_bn2_g = (const float*)d_in[15];
  const float* pt_bn2_b = (const float*)d_in[16];
  const float* sa_qk_w  = (const float*)d_in[17];
  const float* sa_v_w   = (const float*)d_in[18];
  const float* sa_v_b   = (const float*)d_in[19];
  const float* sa_t_w   = (const float*)d_in[20];
  const float* sa_t_b   = (const float*)d_in[21];
  const float* sa_bn_g  = (const float*)d_in[22];
  const float* sa_bn_b  = (const float*)d_in[23];
  const float* fuse_w   = (const float*)d_in[24];
  const float* fuse_g   = (const float*)d_in[25];
  const float* fuse_b   = (const float*)d_in[26];
  const float* lin1_w   = (const float*)d_in[27];
  const float* bn6_g    = (const float*)d_in[28];
  const float* bn6_b    = (const float*)d_in[29];
  const float* lin2_w   = (const float*)d_in[30];
  const float* lin2_b   = (const float*)d_in[31];
  const float* bn7_g    = (const float*)d_in[32];
  const float* bn7_b    = (const float*)d_in[33];
  const float* lin3_w   = (const float*)d_in[34];
  const float* lin3_b   = (const float*)d_in[35];

  float* ws = (float*)d_ws;
  // ---- workspace layout (float offsets) ----
  const size_t oPts  = 0;                         // 49152
  const size_t oS    = 65536;                     // 16777216 f scratch (aliased per phase)
  const size_t oBigT = oS + 16777216;             // 10485760 (bf16 [16][1024][1280])
  const size_t oXf0  = oBigT + 10485760;          // 4194304
  const size_t oXf1  = oXf0 + 4194304;            // 4194304
  const size_t oH1T  = oXf1 + 4194304;            // 2097152 (h1T / diffT alias)
  const size_t oH2T  = oH1T + 2097152;            // 2097152
  const size_t oXkT  = oH2T + 2097152;            // 524288
  const size_t oXv   = oXkT + 524288;             // 2097152
  const size_t oAux  = oXv + 2097152;             // 8388608: phase1 eAT+J; phase2 part
  const size_t oGb   = oAux + 8388608;            // 4194304 (bf16 [16384][512])
  const size_t oW1c  = oGb + 4194304;             // 131072
  const size_t oW2c  = oW1c + 131072;             // 131072
  const size_t oCb1  = oW2c + 131072;             // 512
  const size_t oCb2  = oCb1 + 512;                // 512
  const size_t oPool = oCb2 + 512;                // 16384
  const size_t oFc1  = oPool + 16384;             // 8192
  const size_t oFc2  = oFc1 + 8192;               // 4096
  const size_t oWp   = oFc2 + 4096;               // bf16 weight pool

  float*  pts  = ws + oPts;
  float2* eA   = (float2*)(ws + oS);
  float2* Mj   = (float2*)(ws + oS + 8388608);
  u16*    G1b  = (u16*)(ws + oS);
  u16*    G2b  = (u16*)(ws + oS + 8388608);
  u16*    Eb   = (u16*)(ws + oS);                 // bf16 [16][1024][1024] = 8388608 f
  float*  poolP= ws + oS + 8388608;               // [16][8][1024]
  u16*    bigT = (u16*)(ws + oBigT);
  float*  Xf0  = ws + oXf0;
  float*  Xf1  = ws + oXf1;
  u16*    h1T  = (u16*)(ws + oH1T);
  u16*    diffT= (u16*)(ws + oH1T);
  u16*    h2T  = (u16*)(ws + oH2T);
  u16*    xkT  = (u16*)(ws + oXkT);
  u16*    xv   = (u16*)(ws + oXv);
  u16*    eAT  = (u16*)(ws + oAux);               // phase1
  u16*    Jb   = (u16*)(ws + oAux + 4194304);     // phase1
  float*  partP= ws + oAux;                       // phase2 (eAT dead): [16][1024][8][2]
  u16*    Gb   = (u16*)(ws + oGb);
  u16*    W1c  = (u16*)(ws + oW1c);
  u16*    W2c  = (u16*)(ws + oW2c);
  float*  cb1  = ws + oCb1;
  float*  cb2  = ws + oCb2;
  u16*    wp   = (u16*)(ws + oWp);
  u16* wp_pt1  = wp;                // 65536
  u16* wp_pt2  = wp + 65536;        // 65536
  u16* wp_qkv  = wp + 131072;       // 4 x 320*256 = 327680
  u16* wp_t    = wp + 458752;       // 4*65536
  u16* wp_fuse = wp + 720896;       // 1310720

  // ---- merged prep (pts + all weight casts, 1 launch) ----
  k_prep<<<10052, 256, 0, stream>>>(x, pts,
      pt_c1_w, pt_c2_w, sa_qk_w, sa_v_w, sa_t_w, fuse_w,
      cl1_wr, cl1_wi, cl2_wr, cl2_wi, cl1_br, cl1_bi, cl2_br, cl2_bi,
      wp_pt1, wp_pt2, wp_qkv, wp_t, wp_fuse, W1c, W2c, cb1, cb2);

  // ---- VecKM: fused phase/eAT/jbuild, then M = J @ eA via MFMA ----
  k_pe<<<18432, 256, 0, stream>>>(pts, A, eA, eAT, Jb);
  k_mm<128,0,0><<<512, 256, 0, stream>>>(Jb, 1048576, 1024, eAT, 524288, 1024, 1024, 8, 4,
      nullptr, nullptr, nullptr, nullptr, 0, nullptr, 0, 0,
      (float*)Mj, 524288, 512, nullptr, 0, 0, 0, nullptr, 0, 0, nullptr, nullptr);
  k_norm<<<BB * NN, 256, 0, stream>>>(Mj, eA, pts, P, Gb);

  // ---- complex linears as single real MFMA GEMMs (K=512) ----
  k_mm<128,0,0><<<512, 256, 0, stream>>>(Gb, 0, 512, W1c, 0, 512, 512, 128, 4,
      nullptr, nullptr, nullptr, cb1, 1, nullptr, 0, 0,
      nullptr, 0, 0, G1b, 0, 512, 1, nullptr, 0, 0, nullptr, nullptr);
  k_mm<128,0,0><<<512, 256, 0, stream>>>(G1b, 0, 512, W2c, 0, 512, 512, 128, 4,
      nullptr, nullptr, nullptr, cb2, 0, nullptr, 0, 0,
      nullptr, 0, 0, G2b, 0, 512, 1, nullptr, 0, 0, nullptr, nullptr);
  k_g2<<<16384, 256, 0, stream>>>(G2b, bigT);

  const long bsBigT = 1310720;   // ushort units
  const long bsH256 = 262144;
  const long bsXkT  = 65536;
  const long bsXvU  = 262144;
  const long bsF    = 262144;
  const long bsEU   = 1048576;   // Eb bf16 [1024][1024]

  // ---- pt convs ----
  k_mm<128,0,0><<<256, 256, 0, stream>>>(wp_pt1, 0, 256, bigT + 1024, bsBigT, 1280, 256, 2, 8,
      nullptr, pt_bn1_g, pt_bn1_b, nullptr, 1, nullptr, 0, 0,
      nullptr, 0, 0, nullptr, 0, 0, 0, h1T, bsH256, 256, nullptr, nullptr);
  k_mm<128,0,0><<<256, 256, 0, stream>>>(wp_pt2, 0, 256, h1T, bsH256, 256, 256, 2, 8,
      nullptr, pt_bn2_g, pt_bn2_b, nullptr, 1, nullptr, 0, 0,
      Xf0, bsF, 1024, nullptr, 0, 0, 0, h2T, bsH256, 256, nullptr, nullptr);

  // ---- 4 SA layers ----
  for (int i = 0; i < 4; i++) {
    const u16* XinT   = (i == 0) ? h2T : (bigT + (i - 1) * 256);
    long       xinT_bs= (i == 0) ? bsH256 : bsBigT;
    int        xinT_ld= (i == 0) ? 256 : 1280;
    float*     XinF   = (i & 1) ? Xf1 : Xf0;
    float*     XoutF  = (i & 1) ? Xf0 : Xf1;
    const u16* qkvw = wp_qkv + (size_t)i * 81920;
    const u16* tw   = wp_t + (size_t)i * 65536;

    // fused qkv conv: stacked [320][256] weights; tile0 -> xkT [n][64], tiles1-4 -> xv [c][n]+bias
    k_mm<64,0,1><<<BB * 5 * 8, 256, 0, stream>>>(qkvw, 0, 256, XinT, xinT_bs, xinT_ld, 256, 5, 8,
        sa_v_b + i * 256, nullptr, nullptr, nullptr, 0, nullptr, 0, 0,
        nullptr, 0, 0, xv, bsXvU, 1024, 0, xkT, bsXkT, 64, nullptr, nullptr);
    // energy E = xkT * xkT^T -> bf16 [n][m] + fused per-tile softmax stats
    k_mm<128,1,0><<<1024, 256, 0, stream>>>(xkT, bsXkT, 64, xkT, bsXkT, 64, 64, 8, 8,
        nullptr, nullptr, nullptr, nullptr, 0, nullptr, 0, 0,
        nullptr, 0, 0, Eb, bsEU, 1024, 0, nullptr, 0, 0, nullptr, partP);
    k_xratt<<<512, 256, 0, stream>>>(xv, Eb, partP, XinF, bsF, diffT);
    // t conv: relu(bn(tw@diff + tb)) + Xin -> XoutF fp32 + bigT slice bf16
    k_mm<128,0,0><<<256, 256, 0, stream>>>(tw, 0, 256, diffT, bsH256, 256, 256, 2, 8,
        sa_t_b + i * 256, sa_bn_g + i * 256, sa_bn_b + i * 256, nullptr, 1,
        XinF, bsF, 0,
        XoutF, bsF, 1024, nullptr, 0, 0, 0, bigT + i * 256, bsBigT, 1280, nullptr, nullptr);
  }

  // ---- fuse conv with fused max pool ----
  k_mm<128,0,0><<<1024, 256, 0, stream>>>(wp_fuse, 0, 1280, bigT, bsBigT, 1280, 1280, 8, 8,
      nullptr, fuse_g, fuse_b, nullptr, 2, nullptr, 0, 0,
      nullptr, 0, 0, nullptr, 0, 0, 0, nullptr, 0, 0, poolP, nullptr);

  // ---- fused MLP head (pool + fc1 + fc2 + fc3) ----
  k_head<<<16, 256, 0, stream>>>(poolP, lin1_w, bn6_g, bn6_b,
      lin2_w, lin2_b, bn7_g, bn7_b, lin3_w, lin3_b, (float*)d_out);
}

// Round 11
// 983.980 us; speedup vs baseline: 1.1320x; 1.0046x over previous
//
#include <hip/hip_runtime.h>
#include <math.h>

#define BB 16
#define NN 1024
#define DD 256

typedef unsigned short u16;
typedef unsigned int uint32;
typedef __attribute__((ext_vector_type(8))) short s8v;   // 8 bf16 (4 VGPRs)
typedef __attribute__((ext_vector_type(4))) float f4v;   // 4 fp32 acc

__device__ __forceinline__ u16 f2b(float f) {            // RNE fp32->bf16
  uint32 u = __float_as_uint(f);
  return (u16)((u + 0x7fffu + ((u >> 16) & 1u)) >> 16);
}
__device__ __forceinline__ float b2f(u16 u) {
  return __uint_as_float(((uint32)u) << 16);
}
__device__ __forceinline__ float blo(uint32 w) { return __uint_as_float(w << 16); }
__device__ __forceinline__ float bhi(uint32 w) { return __uint_as_float(w & 0xffff0000u); }

// async global->LDS DMA, 16B per lane; lds base must be wave-uniform (HW scatters +lane*16B)
__device__ __forceinline__ void gld16(u16* lds, const u16* g) {
  __builtin_amdgcn_global_load_lds(
      (const __attribute__((address_space(1))) unsigned int*)g,
      (__attribute__((address_space(3))) unsigned int*)lds, 16, 0, 0);
}

__device__ __forceinline__ float waveRedSum(float v) {
  #pragma unroll
  for (int o = 32; o; o >>= 1) v += __shfl_xor(v, o, 64);
  return v;
}

// ---------------------------------------------------------------- merged prep: pts + all weight casts
__global__ void k_prep(const float* __restrict__ x, float* __restrict__ pts,
                       const float* __restrict__ pt1w, const float* __restrict__ pt2w,
                       const float* __restrict__ qkw, const float* __restrict__ vw,
                       const float* __restrict__ tw, const float* __restrict__ fw,
                       const float* __restrict__ w1r, const float* __restrict__ w1i,
                       const float* __restrict__ w2r, const float* __restrict__ w2i,
                       const float* __restrict__ b1r, const float* __restrict__ b1i,
                       const float* __restrict__ b2r, const float* __restrict__ b2i,
                       u16* __restrict__ wp_pt1, u16* __restrict__ wp_pt2,
                       u16* __restrict__ wp_qkv, u16* __restrict__ wp_t,
                       u16* __restrict__ wp_fuse,
                       u16* __restrict__ W1c, u16* __restrict__ W2c,
                       float* __restrict__ cb1, float* __restrict__ cb2) {
  int i = blockIdx.x * 256 + threadIdx.x;
  if (i < 16384) {
    int b = i >> 10, n = i & 1023;
    const float* xb = x + (size_t)b * 3072;
    pts[i * 3 + 0] = xb[n];
    pts[i * 3 + 1] = xb[1024 + n];
    pts[i * 3 + 2] = xb[2048 + n];
  } else if (i < 81920) {
    int k = i - 16384;  wp_pt1[k] = f2b(pt1w[k]);
  } else if (i < 147456) {
    int k = i - 81920;  wp_pt2[k] = f2b(pt2w[k]);
  } else if (i < 475136) {
    int k = i - 147456;
    int layer = k / 81920, rem = k % 81920;
    int r = rem >> 8, c = rem & 255;
    float v = (r < 64) ? qkw[layer * 16384 + r * 256 + c]
                       : vw[layer * 65536 + (r - 64) * 256 + c];
    wp_qkv[k] = f2b(v);
  } else if (i < 737280) {
    int k = i - 475136; wp_t[k] = f2b(tw[k]);
  } else if (i < 2048000) {
    int k = i - 737280; wp_fuse[k] = f2b(fw[k]);
  } else if (i < 2310144) {
    int k = i - 2048000;
    int op = k >> 9, c2 = k & 511, c = c2 >> 1, pl = c2 & 1;
    float v;
    if (op < 256) v = pl ? -w1i[op * 256 + c] : w1r[op * 256 + c];
    else          v = pl ?  w1r[(op - 256) * 256 + c] : w1i[(op - 256) * 256 + c];
    W1c[k] = f2b(v);
  } else if (i < 2572288) {
    int k = i - 2310144;
    int op = k >> 9, c2 = k & 511, c = c2 >> 1, pl = c2 & 1;
    float v;
    if (op < 256) v = pl ? -w2i[op * 256 + c] : w2r[op * 256 + c];
    else          v = pl ?  w2r[(op - 256) * 256 + c] : w2i[(op - 256) * 256 + c];
    W2c[k] = f2b(v);
  } else if (i < 2572800) {
    int k = i - 2572288; cb1[k] = (k < 256) ? b1r[k] : b1i[k - 256];
  } else if (i < 2573312) {
    int k = i - 2572800; cb2[k] = (k < 256) ? b2r[k] : b2i[k - 256];
  }
}

// ---------------------------------------------------------------- fused phase+eAT (tiles) + jbuild (region)
__global__ void k_pe(const float* __restrict__ pts, const float* __restrict__ A,
                     float2* __restrict__ eA, u16* __restrict__ eAT,
                     u16* __restrict__ J) {
  __shared__ u16 cosT[32][72], sinT[32][72];
  int bid = blockIdx.x;
  int t = threadIdx.x;
  if (bid < 2048) {
    int dt = bid & 7, nt = (bid >> 3) & 15, b = bid >> 7;
    int d0 = dt * 32, n0 = nt * 64;
    int n = t >> 2, dg = (t & 3) * 8;
    const float* pp = pts + ((size_t)(b * 1024 + n0 + n)) * 3;
    float p0 = pp[0], p1 = pp[1], p2 = pp[2];
    float2 ev[8];
    #pragma unroll
    for (int j = 0; j < 8; j++) {
      int d = d0 + dg + j;
      float ta = p0 * A[d] + p1 * A[256 + d] + p2 * A[512 + d];
      float s, c; sincosf(ta, &s, &c);
      ev[j] = make_float2(c, s);
      cosT[dg + j][n] = f2b(c);
      sinT[dg + j][n] = f2b(s);
    }
    float2* dst = eA + ((size_t)(b * 1024 + n0 + n)) * 256 + d0 + dg;
    #pragma unroll
    for (int j = 0; j < 8; j++) dst[j] = ev[j];
    __syncthreads();
    {
      int rr = t >> 2, ng = (t & 3) * 16;
      int d = rr >> 1, cmp = rr & 1;
      const u16* src = (cmp ? &sinT[d][ng] : &cosT[d][ng]);
      uint4 v0 = *(const uint4*)src;
      uint4 v1 = *(const uint4*)(src + 8);
      u16* dstT = eAT + ((size_t)(b * 512 + 2 * d0 + rr)) * 1024 + n0 + ng;
      *(uint4*)dstT = v0;
      *(uint4*)(dstT + 8) = v1;
    }
  } else {
    int bid2 = bid - 2048;
    int b = bid2 >> 10, n = bid2 & 1023;
    const float* pb = pts + (size_t)b * 3072;
    float pnx = pb[n * 3], pny = pb[n * 3 + 1], pnz = pb[n * 3 + 2];
    int m = t * 4;
    const float* pm = pb + (size_t)m * 3;
    float4 a = *(const float4*)pm;
    float4 bq = *(const float4*)(pm + 4);
    float4 c = *(const float4*)(pm + 8);
    float dx, dy, dz, d2;
    dx = a.x - pnx;  dy = a.y - pny;  dz = a.z - pnz;  d2 = dx*dx + dy*dy + dz*dz;
    float j0 = __expf(-18.0f * d2);
    dx = a.w - pnx;  dy = bq.x - pny; dz = bq.y - pnz; d2 = dx*dx + dy*dy + dz*dz;
    float j1 = __expf(-18.0f * d2);
    dx = bq.z - pnx; dy = bq.w - pny; dz = c.x - pnz;  d2 = dx*dx + dy*dy + dz*dz;
    float j2 = __expf(-18.0f * d2);
    dx = c.y - pnx;  dy = c.z - pny;  dz = c.w - pnz;  d2 = dx*dx + dy*dy + dz*dz;
    float j3 = __expf(-18.0f * d2);
    uint32 lo = (uint32)f2b(j0) | ((uint32)f2b(j1) << 16);
    uint32 hi = (uint32)f2b(j2) | ((uint32)f2b(j3) << 16);
    *(uint2*)(J + (size_t)bid2 * 1024 + m) = make_uint2(lo, hi);
  }
}

// ------------------------------------------ G = norm(M*conj(eA))*16 + exp(i pts@P) -> interleaved bf16 [bn][512]
__global__ void k_norm(const float2* __restrict__ M, const float2* __restrict__ eA,
                       const float* __restrict__ pts, const float* __restrict__ P,
                       u16* __restrict__ Gb) {
  int bn = blockIdx.x; int c = threadIdx.x;
  size_t idx = (size_t)bn * DD + c;
  float2 m = M[idx], e = eA[idx];
  float gr = m.x * e.x + m.y * e.y;
  float gi = m.y * e.x - m.x * e.y;
  float s = gr * gr + gi * gi;
  s = waveRedSum(s);
  __shared__ float red[4];
  if ((c & 63) == 0) red[c >> 6] = s;
  __syncthreads();
  float tot = red[0] + red[1] + red[2] + red[3];
  float scale = 16.0f / sqrtf(tot);
  float p0 = pts[bn * 3], p1 = pts[bn * 3 + 1], p2 = pts[bn * 3 + 2];
  float tp = p0 * P[c] + p1 * P[256 + c] + p2 * P[512 + c];
  float sp, cp; sincosf(tp, &sp, &cp);
  uint32 pk = (uint32)f2b(gr * scale + cp) | ((uint32)f2b(gi * scale + sp) << 16);
  *(uint32*)(Gb + idx * 2) = pk;
}

// ---------------------------------------------------------------- Gr=|G|^2 -> bigT[:,1024+c] bf16
__global__ void k_g2(const u16* __restrict__ G2b, u16* __restrict__ bigT) {
  int i = blockIdx.x * 256 + threadIdx.x;   // 16384*256
  int row = i >> 8, c = i & 255;
  float re = b2f(G2b[(size_t)row * 512 + 2 * c]);
  float im = b2f(G2b[(size_t)row * 512 + 2 * c + 1]);
  bigT[(size_t)row * 1280 + 1024 + c] = f2b(re * re + im * im);
}

// ---------------------------------------------------------------- generic bf16 MFMA GEMM
// D[M][N] = A[M][K] * Bt[N][K]^T  (both bf16, k-contiguous), fp32 accum.
// Staging via global_load_lds width=16; XOR-swizzled LDS chunk positions:
//   LDS[row][pos] holds global k-chunk pos^((row>>1)&3) -> 2-way (free) bank access.
template<int BM, int STATS, int QKV>
__launch_bounds__(256)
__global__ void k_mm(const u16* __restrict__ Ab, long a_bs, int lda,
                     const u16* __restrict__ Btb, long b_bs, int ldb,
                     int K, int tiles_m, int tiles_n,
                     const float* __restrict__ bias,
                     const float* __restrict__ bng, const float* __restrict__ bnb,
                     const float* __restrict__ cbias,
                     int act,
                     const float* __restrict__ res, long res_bs, int res_sub,
                     float* __restrict__ outF, long outF_bs, int ldF,
                     u16* __restrict__ outB, long outB_bs, int ldBo, int ileave,
                     u16* __restrict__ outT, long outT_bs, int ldT,
                     float* __restrict__ outPool,
                     float* __restrict__ outStats) {
  constexpr int BN = 128;
  constexpr int WM = (BM == 128) ? 64 : 32;
  constexpr int MI = WM / 16;
  __shared__ u16 smem[BN * BM];            // >= As(BM*32)+Bs(BN*32); also T[BN][BM] / reductions
  u16* As = smem;
  u16* Bs = smem + BM * 32;
  int t = threadIdx.x;
  int l = t & 63, w = t >> 6;
  int p = l & 15, q = l >> 4;
  int bid = blockIdx.x;
  int tn = bid % tiles_n;
  int tm = (bid / tiles_n) % tiles_m;
  int b  = bid / (tiles_n * tiles_m);
  int m0 = tm * BM, n0 = tn * BN;
  int wm = w >> 1, wn = w & 1;
  const u16* Ap = Ab + (size_t)b * a_bs;
  const u16* Bp = Btb + (size_t)b * b_bs;

  f4v acc[MI][4];
  #pragma unroll
  for (int i = 0; i < MI; i++)
    #pragma unroll
    for (int j = 0; j < 4; j++) acc[i][j] = (f4v){0.f, 0.f, 0.f, 0.f};

  int arow = t >> 2;
  int swz = (((t & 3) ^ ((t >> 3) & 3))) * 8;       // swizzled global k-chunk for DMA
  int qa  = (q ^ ((p >> 1) & 3)) * 8;               // swizzled LDS read position
  for (int k0 = 0; k0 < K; k0 += 32) {
    __syncthreads();
    #pragma unroll
    for (int it = 0; it < BM / 64; it++)
      gld16(As + it * 2048 + w * 512,
            Ap + (size_t)(m0 + it * 64 + arow) * lda + k0 + swz);
    #pragma unroll
    for (int it = 0; it < 2; it++)
      gld16(Bs + it * 2048 + w * 512,
            Bp + (size_t)(n0 + it * 64 + arow) * ldb + k0 + swz);
    __syncthreads();
    s8v af[MI], bf[4];
    #pragma unroll
    for (int i = 0; i < MI; i++)
      af[i] = *(const s8v*)&As[(wm * WM + i * 16 + p) * 32 + qa];
    #pragma unroll
    for (int j = 0; j < 4; j++)
      bf[j] = *(const s8v*)&Bs[(wn * 64 + j * 16 + p) * 32 + qa];
    #pragma unroll
    for (int i = 0; i < MI; i++)
      #pragma unroll
      for (int j = 0; j < 4; j++)
        acc[i][j] = __builtin_amdgcn_mfma_f32_16x16x32_bf16(af[i], bf[j], acc[i][j], 0, 0, 0);
  }

  __syncthreads();   // LDS reuse (transpose / reductions)

  u16* oB = outB;
  u16* oT = outT;
  if (QKV) { if (tm == 0) oB = nullptr; else oT = nullptr; }

  float cbv[4];
  #pragma unroll
  for (int j = 0; j < 4; j++) {
    int no = n0 + wn * 64 + j * 16 + p;
    cbv[j] = cbias ? cbias[no] : 0.0f;
  }
  float pmax[MI][4];
  #pragma unroll
  for (int i = 0; i < MI; i++)
    #pragma unroll
    for (int r = 0; r < 4; r++) pmax[i][r] = -3.0e38f;
  const float BNS = 0.99999500003749966f;  // 1/sqrt(1+1e-5)
  #pragma unroll
  for (int i = 0; i < MI; i++) {
    #pragma unroll
    for (int r = 0; r < 4; r++) {
      int mo = m0 + wm * WM + i * 16 + q * 4 + r;
      float mult = 1.f, add = 0.f;
      if (QKV) {
        if (tm > 0 && bias) add = bias[mo - 64];
      } else {
        if (bias) add = bias[mo];
        if (bng) { float s = bng[mo] * BNS; add = add * s + bnb[mo]; mult = s; }
      }
      #pragma unroll
      for (int j = 0; j < 4; j++) {
        int no = n0 + wn * 64 + j * 16 + p;
        float v = acc[i][j][r];
        v = v * mult + add;
        if (cbias) v += cbv[j];
        if (act == 1) v = fmaxf(v, 0.f);
        else if (act == 2) v = v > 0.f ? v : 0.2f * v;
        if (res) {
          float rv = res[(size_t)b * res_bs + (size_t)mo * NN + no];
          v = res_sub ? rv - v : rv + v;
        }
        if (outPool) pmax[i][r] = fmaxf(pmax[i][r], v);
        if (outF) outF[(size_t)b * outF_bs + (size_t)mo * ldF + no] = v;
        if (oB) {
          int moB = QKV ? (mo - 64) : mo;
          int noo = ileave ? (((no & 255) << 1) | (no >> 8)) : no;
          oB[(size_t)b * outB_bs + (size_t)moB * ldBo + noo] = f2b(v);
        }
        if (oT) smem[(wn * 64 + j * 16 + p) * BM + (mo - m0)] = f2b(v);
      }
    }
  }
  if (oT) {
    __syncthreads();
    constexpr int CPR = BM / 8;            // threads per row (8 bf16 each)
    constexpr int RPP = 256 / CPR;
    int row0 = t / CPR, cg = (t % CPR) * 8;
    for (int rr = row0; rr < BN; rr += RPP) {
      float4 v = *(const float4*)&smem[rr * BM + cg];
      *(float4*)(oT + (size_t)b * outT_bs + (size_t)(n0 + rr) * ldT + m0 + cg) = v;
    }
  }
  if (outPool) {
    float* pf = (float*)smem;              // [BM][2]
    #pragma unroll
    for (int i = 0; i < MI; i++)
      #pragma unroll
      for (int r = 0; r < 4; r++) {
        float m = pmax[i][r];
        #pragma unroll
        for (int o = 1; o < 16; o <<= 1) m = fmaxf(m, __shfl_xor(m, o, 64));
        if (p == 0) pf[(wm * WM + i * 16 + q * 4 + r) * 2 + wn] = m;
      }
    __syncthreads();
    if (t < BM) {
      float mv = fmaxf(pf[t * 2], pf[t * 2 + 1]);
      outPool[((size_t)b * tiles_n + tn) * (size_t)(tiles_m * BM) + m0 + t] = mv;
    }
  }
  if (STATS) {
    float* sm1 = (float*)smem;             // [BM][2] max
    float* sm2 = sm1 + BM * 2;             // [BM][2] expsum
    #pragma unroll
    for (int i = 0; i < MI; i++)
      #pragma unroll
      for (int r = 0; r < 4; r++) {
        float m = fmaxf(fmaxf(acc[i][0][r], acc[i][1][r]), fmaxf(acc[i][2][r], acc[i][3][r]));
        #pragma unroll
        for (int o = 1; o < 16; o <<= 1) m = fmaxf(m, __shfl_xor(m, o, 64));
        if (p == 0) sm1[(wm * WM + i * 16 + q * 4 + r) * 2 + wn] = m;
      }
    __syncthreads();
    #pragma unroll
    for (int i = 0; i < MI; i++)
      #pragma unroll
      for (int r = 0; r < 4; r++) {
        int row = wm * WM + i * 16 + q * 4 + r;
        float g = fmaxf(sm1[row * 2], sm1[row * 2 + 1]);
        float s = __expf(acc[i][0][r] - g) + __expf(acc[i][1][r] - g) +
                  __expf(acc[i][2][r] - g) + __expf(acc[i][3][r] - g);
        #pragma unroll
        for (int o = 1; o < 16; o <<= 1) s += __shfl_xor(s, o, 64);
        if (p == 0) sm2[row * 2 + wn] = s;
      }
    __syncthreads();
    if (t < BM) {
      float g = fmaxf(sm1[t * 2], sm1[t * 2 + 1]);
      float ssum = sm2[t * 2] + sm2[t * 2 + 1];
      *(float2*)(outStats + (((size_t)b * (tiles_m * BM) + m0 + t) * tiles_n + tn) * 2)
          = make_float2(g, ssum);
    }
  }
}

// ---------------------------------------------------------------- fused softmax+colsum+xr+diff (E bf16, symmetric)
// m-tile 64 (grid 512). Swizzled LDS tiles as in k_mm.
__launch_bounds__(256)
__global__ void k_xratt(const u16* __restrict__ xv_, const u16* __restrict__ E,
                        const float* __restrict__ part_,
                        const float* __restrict__ XinF, long xinF_bs,
                        u16* __restrict__ diffT) {
  __shared__ u16 smem[16384];          // As(0..4095) Bs(4096..6143); reuse: T[64][128]
  __shared__ float colred[64][4];
  __shared__ float rmS[1024];
  __shared__ float riS[1024];
  u16* As = smem;
  u16* Bs = smem + 4096;
  int t = threadIdx.x;
  int l = t & 63, w = t >> 6;
  int p = l & 15, q = l >> 4;
  int bid = blockIdx.x;
  int mt = bid & 15, ct = (bid >> 4) & 1, b = bid >> 5;
  int c0 = ct * 128, m0 = mt * 64;
  int wm = w;                          // wave covers c-slice wm*32
  const u16* Ap = xv_ + (size_t)b * 262144;
  const u16* Ep = E + ((size_t)b << 20);
  // prologue: combine 8 tile-partials per row -> rmax, 1/expsum
  {
    const float2* pbase = (const float2*)(part_ + (size_t)b * 16384);
    for (int row = t; row < 1024; row += 256) {
      const float2* pp = pbase + row * 8;
      float2 vv[8];
      #pragma unroll
      for (int k = 0; k < 8; k++) vv[k] = pp[k];
      float g = vv[0].x;
      #pragma unroll
      for (int k = 1; k < 8; k++) g = fmaxf(g, vv[k].x);
      float s = 0.f;
      #pragma unroll
      for (int k = 0; k < 8; k++) s += vv[k].y * __expf(vv[k].x - g);
      rmS[row] = g;
      riS[row] = 1.0f / s;
    }
  }
  f4v acc[2][4];
  #pragma unroll
  for (int i = 0; i < 2; i++)
    #pragma unroll
    for (int j = 0; j < 4; j++) acc[i][j] = (f4v){0.f, 0.f, 0.f, 0.f};
  float colpart = 0.f;
  int arow = t >> 2, kg = (t & 3) * 8;
  int swz = (((t & 3) ^ ((t >> 3) & 3))) * 8;
  int qa  = (q ^ ((p >> 1) & 3)) * 8;
  for (int k0 = 0; k0 < 1024; k0 += 32) {
    __syncthreads();
    #pragma unroll
    for (int it = 0; it < 2; it++)
      gld16(As + it * 2048 + w * 512,
            Ap + (size_t)(c0 + it * 64 + arow) * 1024 + k0 + swz);
    float4 ma0 = *(const float4*)&rmS[k0 + kg];
    float4 ma1 = *(const float4*)&rmS[k0 + kg + 4];
    float4 ia0 = *(const float4*)&riS[k0 + kg];
    float4 ia1 = *(const float4*)&riS[k0 + kg + 4];
    {
      int r = arow;                    // m row 0..63
      uint4 e8 = *(const uint4*)(Ep + (size_t)(m0 + r) * 1024 + k0 + kg);
      float p0 = __expf(blo(e8.x) - ma0.x) * ia0.x;
      float p1 = __expf(bhi(e8.x) - ma0.y) * ia0.y;
      float p2 = __expf(blo(e8.y) - ma0.z) * ia0.z;
      float p3 = __expf(bhi(e8.y) - ma0.w) * ia0.w;
      float p4 = __expf(blo(e8.z) - ma1.x) * ia1.x;
      float p5 = __expf(bhi(e8.z) - ma1.y) * ia1.y;
      float p6 = __expf(blo(e8.w) - ma1.z) * ia1.z;
      float p7 = __expf(bhi(e8.w) - ma1.w) * ia1.w;
      float s8 = ((p0 + p1) + (p2 + p3)) + ((p4 + p5) + (p6 + p7));
      colpart += s8;
      uint32 w0 = (uint32)f2b(p0) | ((uint32)f2b(p1) << 16);
      uint32 w1 = (uint32)f2b(p2) | ((uint32)f2b(p3) << 16);
      uint32 w2 = (uint32)f2b(p4) | ((uint32)f2b(p5) << 16);
      uint32 w3 = (uint32)f2b(p6) | ((uint32)f2b(p7) << 16);
      *(uint4*)&Bs[r * 32 + swz] = make_uint4(w0, w1, w2, w3);
    }
    __syncthreads();
    s8v af[2], bf[4];
    #pragma unroll
    for (int i = 0; i < 2; i++)
      af[i] = *(const s8v*)&As[(wm * 32 + i * 16 + p) * 32 + qa];
    #pragma unroll
    for (int j = 0; j < 4; j++)
      bf[j] = *(const s8v*)&Bs[(j * 16 + p) * 32 + qa];
    #pragma unroll
    for (int i = 0; i < 2; i++)
      #pragma unroll
      for (int j = 0; j < 4; j++)
        acc[i][j] = __builtin_amdgcn_mfma_f32_16x16x32_bf16(af[i], bf[j], acc[i][j], 0, 0, 0);
  }
  colred[arow][t & 3] = colpart;
  __syncthreads();
  float csv[4];
  #pragma unroll
  for (int j = 0; j < 4; j++) {
    int ml = j * 16 + p;
    csv[j] = 1.0f / (1e-9f + colred[ml][0] + colred[ml][1] + colred[ml][2] + colred[ml][3]);
  }
  u16* T = smem;                       // [64 m][128 c]
  #pragma unroll
  for (int i = 0; i < 2; i++) {
    #pragma unroll
    for (int r = 0; r < 4; r++) {
      int cl = wm * 32 + i * 16 + q * 4 + r;
      int c = c0 + cl;
      #pragma unroll
      for (int j = 0; j < 4; j++) {
        int ml = j * 16 + p;
        float v = acc[i][j][r] * csv[j];
        float rv = XinF[(size_t)b * xinF_bs + (size_t)c * 1024 + m0 + ml];
        T[ml * 128 + cl] = f2b(rv - v);
      }
    }
  }
  __syncthreads();
  int rr0 = t >> 4, cg = (t & 15) * 8;
  #pragma unroll
  for (int k = 0; k < 4; k++) {
    int rr = rr0 + k * 16;
    *(float4*)(diffT + (size_t)b * 262144 + (size_t)(m0 + rr) * 256 + c0 + cg) =
        *(const float4*)&T[rr * 128 + cg];
  }
}

// ---------------------------------------------------------------- fused head: pool reduce + fc1 + fc2 + fc3
__global__ void k_head(const float* __restrict__ poolP,
                       const float* __restrict__ lin1_w,
                       const float* __restrict__ bn6_g, const float* __restrict__ bn6_b,
                       const float* __restrict__ lin2_w, const float* __restrict__ lin2_b,
                       const float* __restrict__ bn7_g, const float* __restrict__ bn7_b,
                       const float* __restrict__ lin3_w, const float* __restrict__ lin3_b,
                       float* __restrict__ out) {
  int b = blockIdx.x, t = threadIdx.x;
  __shared__ float pl[1024];
  __shared__ float h1[512];
  __shared__ float h2[256];
  const float BNS = 0.99999500003749966f;
  for (int o = t; o < 1024; o += 256) {
    const float* base = poolP + (size_t)b * 8192 + o;
    float m = base[0];
    #pragma unroll
    for (int tn = 1; tn < 8; tn++) m = fmaxf(m, base[tn * 1024]);
    pl[o] = m;
  }
  __syncthreads();
  for (int o = t; o < 512; o += 256) {
    const float* wp = lin1_w + (size_t)o * 1024;
    float s = 0.f;
    for (int c = 0; c < 1024; c += 4) {
      float4 xv = *(const float4*)(pl + c);
      float4 wv = *(const float4*)(wp + c);
      s += xv.x * wv.x + xv.y * wv.y + xv.z * wv.z + xv.w * wv.w;
    }
    s = s * (bn6_g[o] * BNS) + bn6_b[o];
    h1[o] = s > 0.f ? s : 0.2f * s;
  }
  __syncthreads();
  {
    int o = t;
    const float* wp = lin2_w + (size_t)o * 512;
    float s = 0.f;
    for (int c = 0; c < 512; c += 4) {
      float4 xv = *(const float4*)(h1 + c);
      float4 wv = *(const float4*)(wp + c);
      s += xv.x * wv.x + xv.y * wv.y + xv.z * wv.z + xv.w * wv.w;
    }
    s += lin2_b[o];
    s = s * (bn7_g[o] * BNS) + bn7_b[o];
    h2[o] = s > 0.f ? s : 0.2f * s;
  }
  __syncthreads();
  if (t < 40) {
    const float* wp = lin3_w + (size_t)t * 256;
    float s = 0.f;
    for (int c = 0; c < 256; c += 4) {
      float4 xv = *(const float4*)(h2 + c);
      float4 wv = *(const float4*)(wp + c);
      s += xv.x * wv.x + xv.y * wv.y + xv.z * wv.z + xv.w * wv.w;
    }
    out[b * 40 + t] = s + lin3_b[t];
  }
}

// ---------------------------------------------------------------- host
extern "C" void kernel_launch(void* const* d_in, const int* in_sizes, int n_in,
                              void* d_out, int out_size, void* d_ws, size_t ws_size,
                              hipStream_t stream) {
  const float* x        = (const float*)d_in[0];
  const float* A        = (const float*)d_in[1];
  const float* P        = (const float*)d_in[2];
  const float* cl1_wr   = (const float*)d_in[3];
  const float* cl1_wi   = (const float*)d_in[4];
  const float* cl1_br   = (const float*)d_in[5];
  const float* cl1_bi   = (const float*)d_in[6];
  const float* cl2_wr   = (const float*)d_in[7];
  const float* cl2_wi   = (const float*)d_in[8];
  const float* cl2_br   = (const float*)d_in[9];
  const float* cl2_bi   = (const float*)d_in[10];
  const float* pt_c1_w  = (const float*)d_in[11];
  const float* pt_c2_w  = (const float*)d_in[12];
  const float* pt_bn1_g = (const float*)d_in[13];
  const float* pt_bn1_b = (const float*)d_in[14];
  const float* pt_bn2_g = (const float*)d_in[15];
  const float* pt_bn2_b = (const float*)d_in[16];
  const float* sa_qk_w  = (const float*)d_in[17];
  const float* sa_v_w   = (const float*)d_in[18];
  const float* sa_v_b   = (const float*)d_in[19];
  const float* sa_t_w   = (const float*)d_in[20];
  const float* sa_t_b   = (const float*)d_in[21];
  const float* sa_bn_g  = (const float*)d_in[22];
  const float* sa_bn_b  = (const float*)d_in[23];
  const float* fuse_w   = (const float*)d_in[24];
  const float* fuse_g   = (const float*)d_in[25];
  const float* fuse_b   = (const float*)d_in[26];
  const float* lin1_w   = (const float*)d_in[27];
  const float* bn6_g    = (const float*)d_in[28];
  const float* bn6_b    = (const float*)d_in[29];
  const float* lin2_w   = (const float*)d_in[30];
  const float* lin2_b   = (const float*)d_in[31];
  const float* bn7_g    = (const float*)d_in[32];
  const float* bn7_b    = (const float*)d_in[33];
  const float* lin3_w   = (const float*)d_in[34];
  const float* lin3_b   = (const float*)d_in[35];

  float* ws = (float*)d_ws;
  // ---- workspace layout (float offsets) ----
  const size_t oPts  = 0;                         // 49152
  const size_t oS    = 65536;                     // 16777216 f scratch (aliased per phase)
  const size_t oBigT = oS + 16777216;             // 10485760 (bf16 [16][1024][1280])
  const size_t oXf0  = oBigT + 10485760;          // 4194304
  const size_t oXf1  = oXf0 + 4194304;            // 4194304
  const size_t oH1T  = oXf1 + 4194304;            // 2097152 (h1T / diffT alias)
  const size_t oH2T  = oH1T + 2097152;            // 2097152
  const size_t oXkT  = oH2T + 2097152;            // 524288
  const size_t oXv   = oXkT + 524288;             // 2097152
  const size_t oAux  = oXv + 2097152;             // 8388608: phase1 eAT+J; phase2 part
  const size_t oGb   = oAux + 8388608;            // 4194304 (bf16 [16384][512])
  const size_t oW1c  = oGb + 4194304;             // 131072
  const size_t oW2c  = oW1c + 131072;             // 131072
  const size_t oCb1  = oW2c + 131072;             // 512
  const size_t oCb2  = oCb1 + 512;                // 512
  const size_t oPool = oCb2 + 512;                // 16384
  const size_t oFc1  = oPool + 16384;             // 8192
  const size_t oFc2  = oFc1 + 8192;               // 4096
  const size_t oWp   = oFc2 + 4096;               // bf16 weight pool

  float*  pts  = ws + oPts;
  float2* eA   = (float2*)(ws + oS);
  float2* Mj   = (float2*)(ws + oS + 8388608);
  u16*    G1b  = (u16*)(ws + oS);
  u16*    G2b  = (u16*)(ws + oS + 8388608);
  u16*    Eb   = (u16*)(ws + oS);                 // bf16 [16][1024][1024] = 8388608 f
  float*  poolP= ws + oS + 8388608;               // [16][8][1024]
  u16*    bigT = (u16*)(ws + oBigT);
  float*  Xf0  = ws + oXf0;
  float*  Xf1  = ws + oXf1;
  u16*    h1T  = (u16*)(ws + oH1T);
  u16*    diffT= (u16*)(ws + oH1T);
  u16*    h2T  = (u16*)(ws + oH2T);
  u16*    xkT  = (u16*)(ws + oXkT);
  u16*    xv   = (u16*)(ws + oXv);
  u16*    eAT  = (u16*)(ws + oAux);               // phase1
  u16*    Jb   = (u16*)(ws + oAux + 4194304);     // phase1
  float*  partP= ws + oAux;                       // phase2 (eAT dead): [16][1024][8][2]
  u16*    Gb   = (u16*)(ws + oGb);
  u16*    W1c  = (u16*)(ws + oW1c);
  u16*    W2c  = (u16*)(ws + oW2c);
  float*  cb1  = ws + oCb1;
  float*  cb2  = ws + oCb2;
  u16*    wp   = (u16*)(ws + oWp);
  u16* wp_pt1  = wp;                // 65536
  u16* wp_pt2  = wp + 65536;        // 65536
  u16* wp_qkv  = wp + 131072;       // 4 x 320*256 = 327680
  u16* wp_t    = wp + 458752;       // 4*65536
  u16* wp_fuse = wp + 720896;       // 1310720

  // ---- merged prep (pts + all weight casts, 1 launch) ----
  k_prep<<<10052, 256, 0, stream>>>(x, pts,
      pt_c1_w, pt_c2_w, sa_qk_w, sa_v_w, sa_t_w, fuse_w,
      cl1_wr, cl1_wi, cl2_wr, cl2_wi, cl1_br, cl1_bi, cl2_br, cl2_bi,
      wp_pt1, wp_pt2, wp_qkv, wp_t, wp_fuse, W1c, W2c, cb1, cb2);

  // ---- VecKM: fused phase/eAT/jbuild, then M = J @ eA via MFMA ----
  k_pe<<<18432, 256, 0, stream>>>(pts, A, eA, eAT, Jb);
  k_mm<128,0,0><<<512, 256, 0, stream>>>(Jb, 1048576, 1024, eAT, 524288, 1024, 1024, 8, 4,
      nullptr, nullptr, nullptr, nullptr, 0, nullptr, 0, 0,
      (float*)Mj, 524288, 512, nullptr, 0, 0, 0, nullptr, 0, 0, nullptr, nullptr);
  k_norm<<<BB * NN, 256, 0, stream>>>(Mj, eA, pts, P, Gb);

  // ---- complex linears as single real MFMA GEMMs (K=512) ----
  k_mm<128,0,0><<<512, 256, 0, stream>>>(Gb, 0, 512, W1c, 0, 512, 512, 128, 4,
      nullptr, nullptr, nullptr, cb1, 1, nullptr, 0, 0,
      nullptr, 0, 0, G1b, 0, 512, 1, nullptr, 0, 0, nullptr, nullptr);
  k_mm<128,0,0><<<512, 256, 0, stream>>>(G1b, 0, 512, W2c, 0, 512, 512, 128, 4,
      nullptr, nullptr, nullptr, cb2, 0, nullptr, 0, 0,
      nullptr, 0, 0, G2b, 0, 512, 1, nullptr, 0, 0, nullptr, nullptr);
  k_g2<<<16384, 256, 0, stream>>>(G2b, bigT);

  const long bsBigT = 1310720;   // ushort units
  const long bsH256 = 262144;
  const long bsXkT  = 65536;
  const long bsXvU  = 262144;
  const long bsF    = 262144;
  const long bsEU   = 1048576;   // Eb bf16 [1024][1024]

  // ---- pt convs ----
  k_mm<128,0,0><<<256, 256, 0, stream>>>(wp_pt1, 0, 256, bigT + 1024, bsBigT, 1280, 256, 2, 8,
      nullptr, pt_bn1_g, pt_bn1_b, nullptr, 1, nullptr, 0, 0,
      nullptr, 0, 0, nullptr, 0, 0, 0, h1T, bsH256, 256, nullptr, nullptr);
  k_mm<128,0,0><<<256, 256, 0, stream>>>(wp_pt2, 0, 256, h1T, bsH256, 256, 256, 2, 8,
      nullptr, pt_bn2_g, pt_bn2_b, nullptr, 1, nullptr, 0, 0,
      Xf0, bsF, 1024, nullptr, 0, 0, 0, h2T, bsH256, 256, nullptr, nullptr);

  // ---- 4 SA layers ----
  for (int i = 0; i < 4; i++) {
    const u16* XinT   = (i == 0) ? h2T : (bigT + (i - 1) * 256);
    long       xinT_bs= (i == 0) ? bsH256 : bsBigT;
    int        xinT_ld= (i == 0) ? 256 : 1280;
    float*     XinF   = (i & 1) ? Xf1 : Xf0;
    float*     XoutF  = (i & 1) ? Xf0 : Xf1;
    const u16* qkvw = wp_qkv + (size_t)i * 81920;
    const u16* tw   = wp_t + (size_t)i * 65536;

    // fused qkv conv: stacked [320][256] weights; tile0 -> xkT [n][64], tiles1-4 -> xv [c][n]+bias
    k_mm<64,0,1><<<BB * 5 * 8, 256, 0, stream>>>(qkvw, 0, 256, XinT, xinT_bs, xinT_ld, 256, 5, 8,
        sa_v_b + i * 256, nullptr, nullptr, nullptr, 0, nullptr, 0, 0,
        nullptr, 0, 0, xv, bsXvU, 1024, 0, xkT, bsXkT, 64, nullptr, nullptr);
    // energy E = xkT * xkT^T -> bf16 [n][m] + fused per-tile softmax stats
    k_mm<128,1,0><<<1024, 256, 0, stream>>>(xkT, bsXkT, 64, xkT, bsXkT, 64, 64, 8, 8,
        nullptr, nullptr, nullptr, nullptr, 0, nullptr, 0, 0,
        nullptr, 0, 0, Eb, bsEU, 1024, 0, nullptr, 0, 0, nullptr, partP);
    k_xratt<<<512, 256, 0, stream>>>(xv, Eb, partP, XinF, bsF, diffT);
    // t conv: relu(bn(tw@diff + tb)) + Xin -> XoutF fp32 + bigT slice bf16
    k_mm<128,0,0><<<256, 256, 0, stream>>>(tw, 0, 256, diffT, bsH256, 256, 256, 2, 8,
        sa_t_b + i * 256, sa_bn_g + i * 256, sa_bn_b + i * 256, nullptr, 1,
        XinF, bsF, 0,
        XoutF, bsF, 1024, nullptr, 0, 0, 0, bigT + i * 256, bsBigT, 1280, nullptr, nullptr);
  }

  // ---- fuse conv with fused max pool ----
  k_mm<128,0,0><<<1024, 256, 0, stream>>>(wp_fuse, 0, 1280, bigT, bsBigT, 1280, 1280, 8, 8,
      nullptr, fuse_g, fuse_b, nullptr, 2, nullptr, 0, 0,
      nullptr, 0, 0, nullptr, 0, 0, 0, nullptr, 0, 0, poolP, nullptr);

  // ---- fused MLP head (pool + fc1 + fc2 + fc3) ----
  k_head<<<16, 256, 0, stream>>>(poolP, lin1_w, bn6_g, bn6_b,
      lin2_w, lin2_b, bn7_g, bn7_b, lin3_w, lin3_b, (float*)d_out);
}